// Round 1
// baseline (197.333 us; speedup 1.0000x reference)
//
#include <hip/hip_runtime.h>
#include <stdint.h>

typedef float f32x4 __attribute__((ext_vector_type(4)));
typedef __bf16 bf16x8 __attribute__((ext_vector_type(8)));

#define MFMA16(a,b,c) __builtin_amdgcn_mfma_f32_16x16x32_bf16((a),(b),(c),0,0,0)

__device__ __forceinline__ unsigned short f2bf(float f){
  unsigned int u = __float_as_uint(f);
  u += 0x7FFFu + ((u >> 16) & 1u);
  return (unsigned short)(u >> 16);
}

// ---------------- transpose + cast: W(K,N) f32 -> WT(N,K) bf16 ----------------
__global__ __launch_bounds__(256) void k_transpose_cast(
    const float* __restrict__ W, unsigned short* __restrict__ WT, int K, int N)
{
  __shared__ float tile[32][33];
  int bx = blockIdx.x * 32, by = blockIdx.y * 32;
  int tx = threadIdx.x, ty = threadIdx.y;
  #pragma unroll
  for (int i = 0; i < 32; i += 8)
    tile[ty + i][tx] = W[(size_t)(by + ty + i) * N + bx + tx];
  __syncthreads();
  #pragma unroll
  for (int i = 0; i < 32; i += 8)
    WT[(size_t)(bx + ty + i) * K + by + tx] = f2bf(tile[tx][ty + i]);
}

// ---------------- layernorm over 512 cols, one wave per row ----------------
template<int OUTBF>
__global__ __launch_bounds__(256) void k_layernorm(
    const float* __restrict__ X, const float* __restrict__ G,
    const float* __restrict__ Bt, void* __restrict__ out)
{
  int row = blockIdx.x * 4 + (threadIdx.x >> 6);
  int lane = threadIdx.x & 63;
  const float4* xr = (const float4*)(X + (size_t)row * 512);
  float4 a = xr[lane];
  float4 c = xr[64 + lane];
  float s = a.x + a.y + a.z + a.w + c.x + c.y + c.z + c.w;
  #pragma unroll
  for (int o = 32; o; o >>= 1) s += __shfl_xor(s, o);
  float mu = s * (1.0f / 512.0f);
  float va = (a.x-mu)*(a.x-mu) + (a.y-mu)*(a.y-mu) + (a.z-mu)*(a.z-mu) + (a.w-mu)*(a.w-mu)
           + (c.x-mu)*(c.x-mu) + (c.y-mu)*(c.y-mu) + (c.z-mu)*(c.z-mu) + (c.w-mu)*(c.w-mu);
  #pragma unroll
  for (int o = 32; o; o >>= 1) va += __shfl_xor(va, o);
  float inv = rsqrtf(va * (1.0f / 512.0f) + 1e-5f);
  const float4* gp = (const float4*)G;
  const float4* bp = (const float4*)Bt;
  float4 g0 = gp[lane], g1 = gp[64 + lane], b0 = bp[lane], b1 = bp[64 + lane];
  float4 y0, y1;
  y0.x = (a.x - mu) * inv * g0.x + b0.x;
  y0.y = (a.y - mu) * inv * g0.y + b0.y;
  y0.z = (a.z - mu) * inv * g0.z + b0.z;
  y0.w = (a.w - mu) * inv * g0.w + b0.w;
  y1.x = (c.x - mu) * inv * g1.x + b1.x;
  y1.y = (c.y - mu) * inv * g1.y + b1.y;
  y1.z = (c.z - mu) * inv * g1.z + b1.z;
  y1.w = (c.w - mu) * inv * g1.w + b1.w;
  if constexpr (OUTBF) {
    ushort4* op = (ushort4*)((unsigned short*)out + (size_t)row * 512);
    op[lane]      = make_ushort4(f2bf(y0.x), f2bf(y0.y), f2bf(y0.z), f2bf(y0.w));
    op[64 + lane] = make_ushort4(f2bf(y1.x), f2bf(y1.y), f2bf(y1.z), f2bf(y1.w));
  } else {
    float4* op = (float4*)((float*)out + (size_t)row * 512);
    op[lane] = y0;
    op[64 + lane] = y1;
  }
}

// ---------------- f32 -> bf16 cast (vectorized) ----------------
__global__ __launch_bounds__(256) void k_cast_bf16(
    const float* __restrict__ X, unsigned short* __restrict__ Y)
{
  int i = blockIdx.x * 256 + threadIdx.x;
  float4 v = ((const float4*)X)[i];
  ((ushort4*)Y)[i] = make_ushort4(f2bf(v.x), f2bf(v.y), f2bf(v.z), f2bf(v.w));
}

// ---------------- bf16 MFMA GEMM: C(Mr,Nc) = A(Mr,512) * BT(Nc,512)^T ----------------
// 128x128 tile, BK=64, 256 thr (4 waves 2x2, each 64x64), XOR-swizzled LDS.
// MODE 0: bf16 out (stride 512). MODE 1: KV split -> k natural + v transposed.
// MODE 2: f32 out (stride 512).
template<int MODE>
__global__ __launch_bounds__(256) void k_gemm(
    const unsigned short* __restrict__ A, const unsigned short* __restrict__ BT,
    void* __restrict__ out0, void* __restrict__ out1)
{
  __shared__ __align__(16) unsigned short As[128 * 64];
  __shared__ __align__(16) unsigned short Bs[128 * 64];
  const int t = threadIdx.x;
  const int lane = t & 63, l16 = lane & 15, lhi = lane >> 4;
  const int w = t >> 6, wm = w >> 1, wn = w & 1;
  const int rowBase = blockIdx.y * 128;
  const int colBase = blockIdx.x * 128;

  f32x4 acc[4][4];
  #pragma unroll
  for (int i = 0; i < 4; i++)
    #pragma unroll
    for (int j = 0; j < 4; j++)
      acc[i][j] = f32x4{0.f, 0.f, 0.f, 0.f};

  uint4 ra[4], rb[4];
  auto gload = [&](int kt) {
    #pragma unroll
    for (int i = 0; i < 4; i++) {
      int c = i * 256 + t;
      int rr = c >> 3, cw = c & 7;
      ra[i] = *(const uint4*)(A  + (size_t)(rowBase + rr) * 512 + kt * 64 + cw * 8);
      rb[i] = *(const uint4*)(BT + (size_t)(colBase + rr) * 512 + kt * 64 + cw * 8);
    }
  };
  auto lstore = [&]() {
    #pragma unroll
    for (int i = 0; i < 4; i++) {
      int c = i * 256 + t;
      int rr = c >> 3, cw = c & 7, sz = cw ^ (rr & 7);
      *(uint4*)((char*)As + rr * 128 + sz * 16) = ra[i];
      *(uint4*)((char*)Bs + rr * 128 + sz * 16) = rb[i];
    }
  };

  gload(0);
  for (int kt = 0; kt < 8; ++kt) {
    lstore();
    __syncthreads();
    if (kt < 7) gload(kt + 1);
    #pragma unroll
    for (int ks = 0; ks < 2; ++ks) {
      bf16x8 af[4], bb[4];
      #pragma unroll
      for (int mi = 0; mi < 4; mi++) {
        int rr = wm * 64 + mi * 16 + l16;
        int cc = ks * 4 + lhi;
        af[mi] = *(const bf16x8*)((const char*)As + rr * 128 + ((cc ^ (rr & 7)) * 16));
      }
      #pragma unroll
      for (int ni = 0; ni < 4; ni++) {
        int rr = wn * 64 + ni * 16 + l16;
        int cc = ks * 4 + lhi;
        bb[ni] = *(const bf16x8*)((const char*)Bs + rr * 128 + ((cc ^ (rr & 7)) * 16));
      }
      #pragma unroll
      for (int mi = 0; mi < 4; mi++)
        #pragma unroll
        for (int ni = 0; ni < 4; ni++)
          acc[mi][ni] = MFMA16(af[mi], bb[ni], acc[mi][ni]);
    }
    __syncthreads();
  }

  const int r0 = rowBase + wm * 64 + lhi * 4;
  const int c0 = colBase + wn * 64 + l16;
  #pragma unroll
  for (int mi = 0; mi < 4; mi++) {
    #pragma unroll
    for (int ni = 0; ni < 4; ni++) {
      int row = r0 + mi * 16;
      int col = c0 + ni * 16;
      if constexpr (MODE == 0) {
        #pragma unroll
        for (int r = 0; r < 4; r++)
          ((unsigned short*)out0)[(size_t)(row + r) * 512 + col] = f2bf(acc[mi][ni][r]);
      } else if constexpr (MODE == 1) {
        if (col < 512) {
          #pragma unroll
          for (int r = 0; r < 4; r++)
            ((unsigned short*)out0)[(size_t)(row + r) * 512 + col] = f2bf(acc[mi][ni][r]);
        } else {
          int dfull = col - 512, hh = dfull >> 6, dd = dfull & 63;
          int bb2 = row >> 11, mm = row & 2047;
          ushort4 p = make_ushort4(f2bf(acc[mi][ni][0]), f2bf(acc[mi][ni][1]),
                                   f2bf(acc[mi][ni][2]), f2bf(acc[mi][ni][3]));
          *(ushort4*)((unsigned short*)out1 + ((size_t)((bb2 * 8 + hh) * 64 + dd)) * 2048 + mm) = p;
        }
      } else {
        #pragma unroll
        for (int r = 0; r < 4; r++)
          ((float*)out0)[(size_t)(row + r) * 512 + col] = acc[mi][ni][r];
      }
    }
  }
}

// ---------------- flash attention ----------------
// grid (32, 16): x = q-tile (64 rows), y = b*8+h. 4 waves, 16 q-rows each.
// K/V tiles (64 kv) staged in swizzled LDS shared by all waves.
__global__ __launch_bounds__(256) void k_attn(
    const unsigned short* __restrict__ Q, const unsigned short* __restrict__ Kb,
    const unsigned short* __restrict__ VT, const int* __restrict__ mask,
    unsigned short* __restrict__ O)
{
  __shared__ __align__(16) unsigned short Ks[64 * 64];
  __shared__ __align__(16) unsigned short Vs[64 * 64];
  __shared__ __align__(16) unsigned short Plds[4][16][72];
  const int t = threadIdx.x;
  const int lane = t & 63, l16 = lane & 15, lhi = lane >> 4;
  const int w = t >> 6;
  const int bh = blockIdx.y, b = bh >> 3, h = bh & 7;
  const int q0 = blockIdx.x * 64 + w * 16;

  const unsigned short* qrow = Q + (size_t)(b * 2048 + q0 + l16) * 512 + h * 64 + lhi * 8;
  bf16x8 aq0 = *(const bf16x8*)(qrow);
  bf16x8 aq1 = *(const bf16x8*)(qrow + 32);

  const unsigned short* kbase = Kb + (size_t)(b * 2048) * 512 + h * 64;
  const unsigned short* vbase = VT + (size_t)((b * 8 + h) * 64) * 2048;
  const int* mbase = mask + b * 2048;

  float mrun[4] = {-1e30f, -1e30f, -1e30f, -1e30f};
  float lrun[4] = {0.f, 0.f, 0.f, 0.f};
  f32x4 acc[4];
  #pragma unroll
  for (int d = 0; d < 4; d++) acc[d] = f32x4{0.f, 0.f, 0.f, 0.f};

  uint4 rk[2], rv[2];
  auto gload = [&](int jt) {
    int j0 = jt * 64;
    #pragma unroll
    for (int i = 0; i < 2; i++) {
      int c = i * 256 + t;
      int rr = c >> 3, cw = c & 7;
      rk[i] = *(const uint4*)(kbase + (size_t)(j0 + rr) * 512 + cw * 8);
      rv[i] = *(const uint4*)(vbase + (size_t)rr * 2048 + j0 + cw * 8);
    }
  };
  auto lstore = [&]() {
    #pragma unroll
    for (int i = 0; i < 2; i++) {
      int c = i * 256 + t;
      int rr = c >> 3, cw = c & 7, sz = cw ^ (rr & 7);
      *(uint4*)((char*)Ks + rr * 128 + sz * 16) = rk[i];
      *(uint4*)((char*)Vs + rr * 128 + sz * 16) = rv[i];
    }
  };

  gload(0);
  for (int jt = 0; jt < 32; ++jt) {
    const int j0 = jt * 64;
    lstore();
    __syncthreads();
    if (jt < 31) gload(jt + 1);

    // ---- QK^T: sim tile 16 x 64 per wave ----
    f32x4 s[4];
    #pragma unroll
    for (int j = 0; j < 4; j++) s[j] = f32x4{0.f, 0.f, 0.f, 0.f};
    #pragma unroll
    for (int ks = 0; ks < 2; ++ks) {
      #pragma unroll
      for (int jsub = 0; jsub < 4; jsub++) {
        int rr = jsub * 16 + l16;
        int cc = ks * 4 + lhi;
        bf16x8 bk = *(const bf16x8*)((const char*)Ks + rr * 128 + ((cc ^ (rr & 7)) * 16));
        s[jsub] = MFMA16(ks ? aq1 : aq0, bk, s[jsub]);
      }
    }

    // ---- mask + scale ----
    bool okv[4];
    float lg[4][4];
    #pragma unroll
    for (int jsub = 0; jsub < 4; jsub++) {
      okv[jsub] = mbase[j0 + jsub * 16 + l16] != 0;
      #pragma unroll
      for (int r = 0; r < 4; r++)
        lg[jsub][r] = okv[jsub] ? s[jsub][r] * 0.015625f : -1e30f;
    }

    // ---- online softmax (row = lhi*4+r, 16-lane row groups) ----
    #pragma unroll
    for (int r = 0; r < 4; r++) {
      float rm = fmaxf(fmaxf(lg[0][r], lg[1][r]), fmaxf(lg[2][r], lg[3][r]));
      #pragma unroll
      for (int o = 8; o; o >>= 1) rm = fmaxf(rm, __shfl_xor(rm, o));
      float mnew = fmaxf(mrun[r], rm);
      float sf = __expf(mrun[r] - mnew);
      mrun[r] = mnew;
      float pv[4], rs = 0.f;
      #pragma unroll
      for (int jsub = 0; jsub < 4; jsub++) {
        float p = okv[jsub] ? __expf(lg[jsub][r] - mnew) : 0.f;
        pv[jsub] = p;
        rs += p;
      }
      #pragma unroll
      for (int o = 8; o; o >>= 1) rs += __shfl_xor(rs, o);
      lrun[r] = lrun[r] * sf + rs;
      #pragma unroll
      for (int d = 0; d < 4; d++) acc[d][r] *= sf;
      #pragma unroll
      for (int jsub = 0; jsub < 4; jsub++)
        Plds[w][lhi * 4 + r][jsub * 16 + l16] = f2bf(pv[jsub]);
    }

    // ---- PV: A = P (via wave-private LDS), B = V^T tile ----
    #pragma unroll
    for (int ks = 0; ks < 2; ++ks) {
      bf16x8 pa = *(const bf16x8*)((const char*)Plds + w * 2304 + l16 * 144 + ks * 64 + lhi * 16);
      #pragma unroll
      for (int d = 0; d < 4; d++) {
        int rr = d * 16 + l16;
        int cc = ks * 4 + lhi;
        bf16x8 bv = *(const bf16x8*)((const char*)Vs + rr * 128 + ((cc ^ (rr & 7)) * 16));
        acc[d] = MFMA16(pa, bv, acc[d]);
      }
    }
    __syncthreads();
  }

  #pragma unroll
  for (int r = 0; r < 4; r++) {
    float inv = 1.0f / lrun[r];
    size_t orow = (size_t)(b * 2048 + q0 + lhi * 4 + r) * 512 + h * 64;
    #pragma unroll
    for (int d = 0; d < 4; d++)
      O[orow + d * 16 + l16] = f2bf(acc[d][r] * inv);
  }
}

// ---------------- host ----------------
extern "C" void kernel_launch(void* const* d_in, const int* in_sizes, int n_in,
                              void* d_out, int out_size, void* d_ws, size_t ws_size,
                              hipStream_t stream) {
  const float* x     = (const float*)d_in[0];
  const float* ctx   = (const float*)d_in[1];
  const int*   mask  = (const int*)d_in[2];
  const float* ln_g  = (const float*)d_in[3];
  const float* ln_b  = (const float*)d_in[4];
  const float* Wq    = (const float*)d_in[5];
  const float* Wkv   = (const float*)d_in[6];
  const float* Wo    = (const float*)d_in[7];
  const float* lno_g = (const float*)d_in[8];
  const float* lno_b = (const float*)d_in[9];
  float* out = (float*)d_out;

  char* ws = (char*)d_ws;
  unsigned short* WqT  = (unsigned short*)(ws + 0);                    // 512 KB
  unsigned short* WkvT = (unsigned short*)(ws + (size_t)1  * (1 << 20) - (1 << 19)); // @0.5MB, 1MB
  unsigned short* WoT  = (unsigned short*)(ws + (size_t)3  * (1 << 19));             // @1.5MB, 512KB
  unsigned short* xn   = (unsigned short*)(ws + (size_t)2  * (1 << 20));             // @2MB,  4MB
  unsigned short* cb   = (unsigned short*)(ws + (size_t)6  * (1 << 20));
  unsigned short* qb   = (unsigned short*)(ws + (size_t)10 * (1 << 20));
  unsigned short* kb   = (unsigned short*)(ws + (size_t)14 * (1 << 20));
  unsigned short* vT   = (unsigned short*)(ws + (size_t)18 * (1 << 20));
  unsigned short* ao   = (unsigned short*)(ws + (size_t)22 * (1 << 20));
  float* proj          = (float*)(ws + (size_t)26 * (1 << 20));                      // 8MB

  dim3 tb(32, 8);
  k_transpose_cast<<<dim3(16, 16), tb, 0, stream>>>(Wq,  WqT,  512, 512);
  k_transpose_cast<<<dim3(32, 16), tb, 0, stream>>>(Wkv, WkvT, 512, 1024);
  k_transpose_cast<<<dim3(16, 16), tb, 0, stream>>>(Wo,  WoT,  512, 512);
  k_layernorm<1><<<1024, 256, 0, stream>>>(x, ln_g, ln_b, xn);
  k_cast_bf16<<<2048, 256, 0, stream>>>(ctx, cb);
  k_gemm<0><<<dim3(4, 32), 256, 0, stream>>>(xn, WqT, qb, nullptr);
  k_gemm<1><<<dim3(8, 32), 256, 0, stream>>>(cb, WkvT, kb, vT);
  k_attn<<<dim3(32, 16), 256, 0, stream>>>(qb, kb, vT, mask, ao);
  k_gemm<2><<<dim3(4, 32), 256, 0, stream>>>(ao, WoT, proj, nullptr);
  k_layernorm<0><<<1024, 256, 0, stream>>>(proj, lno_g, lno_b, out);
}

// Round 2
// 145.221 us; speedup vs baseline: 1.3588x; 1.3588x over previous
//
#include <hip/hip_runtime.h>
#include <stdint.h>

typedef float f32x4 __attribute__((ext_vector_type(4)));
typedef float f32x16 __attribute__((ext_vector_type(16)));
typedef __bf16 bf16x8 __attribute__((ext_vector_type(8)));
typedef unsigned int uint2v __attribute__((ext_vector_type(2)));

#define MFMA16(a,b,c) __builtin_amdgcn_mfma_f32_16x16x32_bf16((a),(b),(c),0,0,0)
#define MFMA32(a,b,c) __builtin_amdgcn_mfma_f32_32x32x16_bf16((a),(b),(c),0,0,0)

__device__ __forceinline__ unsigned short f2bf(float f){
  unsigned int u = __float_as_uint(f);
  u += 0x7FFFu + ((u >> 16) & 1u);
  return (unsigned short)(u >> 16);
}

__device__ __forceinline__ unsigned cvtpk(float lo, float hi){
  unsigned r;
  asm volatile("v_cvt_pk_bf16_f32 %0, %1, %2" : "=v"(r) : "v"(lo), "v"(hi));
  return r;
}

__device__ __forceinline__ float fexp2(float x){
#if __has_builtin(__builtin_amdgcn_exp2f)
  return __builtin_amdgcn_exp2f(x);
#else
  return exp2f(x);
#endif
}

// permlane32_swap: a' = (lane<32)? a : b[lane-32]; b' = (lane<32)? a[lane+32] : b
__device__ __forceinline__ void plswap(unsigned &a, unsigned &b){
#if __has_builtin(__builtin_amdgcn_permlane32_swap)
  uint2v r = __builtin_amdgcn_permlane32_swap(a, b, false, false);
  a = r[0]; b = r[1];
#else
  unsigned xa = __shfl_xor(a, 32), xb = __shfl_xor(b, 32);
  int hi = (threadIdx.x & 63) >> 5;
  unsigned na = hi ? xb : a;
  unsigned nb = hi ? b : xa;
  a = na; b = nb;
#endif
}

// ---------------- prep router: weight transposes + LN(x) + cast(ctx) + maskbits ----------------
__global__ __launch_bounds__(256) void k_prep(
    const float* __restrict__ Wq, const float* __restrict__ Wkv, const float* __restrict__ Wo,
    const float* __restrict__ x, const float* __restrict__ ln_g, const float* __restrict__ ln_b,
    const float* __restrict__ ctx, const int* __restrict__ mask,
    unsigned short* __restrict__ WqT, unsigned short* __restrict__ WkvT, unsigned short* __restrict__ WoT,
    unsigned short* __restrict__ xn, unsigned short* __restrict__ cb, unsigned int* __restrict__ mb)
{
  __shared__ float tile[32][33];
  const int bid = blockIdx.x, t = threadIdx.x;
  if (bid < 1024) {
    const float* W; unsigned short* WT; int N, bx, by;
    if (bid < 256)      { W = Wq;  WT = WqT;  N = 512;  bx = bid & 15;        by = bid >> 4; }
    else if (bid < 768) { W = Wkv; WT = WkvT; N = 1024; bx = (bid-256) & 31;  by = (bid-256) >> 5; }
    else                { W = Wo;  WT = WoT;  N = 512;  bx = (bid-768) & 15;  by = (bid-768) >> 4; }
    const int tx = t & 31, ty = t >> 5;
    #pragma unroll
    for (int i = 0; i < 4; i++)
      tile[ty + i*8][tx] = W[(size_t)(by*32 + ty + i*8) * N + bx*32 + tx];
    __syncthreads();
    #pragma unroll
    for (int i = 0; i < 4; i++)
      WT[(size_t)(bx*32 + ty + i*8) * 512 + by*32 + tx] = f2bf(tile[tx][ty + i*8]);
  } else if (bid < 2048) {
    // layernorm of x -> xn (bf16); 4 rows/block
    int row = (bid - 1024) * 4 + (t >> 6);
    int lane = t & 63;
    const float4* xr = (const float4*)(x + (size_t)row * 512);
    float4 a = xr[lane], c = xr[64 + lane];
    float s = a.x + a.y + a.z + a.w + c.x + c.y + c.z + c.w;
    #pragma unroll
    for (int o = 32; o; o >>= 1) s += __shfl_xor(s, o);
    float mu = s * (1.0f / 512.0f);
    float va = (a.x-mu)*(a.x-mu) + (a.y-mu)*(a.y-mu) + (a.z-mu)*(a.z-mu) + (a.w-mu)*(a.w-mu)
             + (c.x-mu)*(c.x-mu) + (c.y-mu)*(c.y-mu) + (c.z-mu)*(c.z-mu) + (c.w-mu)*(c.w-mu);
    #pragma unroll
    for (int o = 32; o; o >>= 1) va += __shfl_xor(va, o);
    float inv = rsqrtf(va * (1.0f / 512.0f) + 1e-5f);
    const float4* gp = (const float4*)ln_g;
    const float4* bp = (const float4*)ln_b;
    float4 g0 = gp[lane], g1 = gp[64 + lane], b0 = bp[lane], b1 = bp[64 + lane];
    ushort4* op = (ushort4*)(xn + (size_t)row * 512);
    op[lane]      = make_ushort4(f2bf((a.x-mu)*inv*g0.x + b0.x), f2bf((a.y-mu)*inv*g0.y + b0.y),
                                 f2bf((a.z-mu)*inv*g0.z + b0.z), f2bf((a.w-mu)*inv*g0.w + b0.w));
    op[64 + lane] = make_ushort4(f2bf((c.x-mu)*inv*g1.x + b1.x), f2bf((c.y-mu)*inv*g1.y + b1.y),
                                 f2bf((c.z-mu)*inv*g1.z + b1.z), f2bf((c.w-mu)*inv*g1.w + b1.w));
  } else if (bid < 4096) {
    int i = (bid - 2048) * 256 + t;
    float4 v = ((const float4*)ctx)[i];
    ((ushort4*)cb)[i] = make_ushort4(f2bf(v.x), f2bf(v.y), f2bf(v.z), f2bf(v.w));
  } else {
    int g = (bid - 4096) * 4 + (t >> 6);
    int ln = t & 63;
    int v = mask[g * 64 + ln];
    unsigned long long bb = __ballot(v != 0);
    if (ln == 0) { mb[g*2] = (unsigned)bb; mb[g*2+1] = (unsigned)(bb >> 32); }
  }
}

// ---------------- final layernorm (f32 in/out) ----------------
__global__ __launch_bounds__(256) void k_layernorm_f(
    const float* __restrict__ X, const float* __restrict__ G,
    const float* __restrict__ Bt, float* __restrict__ out)
{
  int row = blockIdx.x * 4 + (threadIdx.x >> 6);
  int lane = threadIdx.x & 63;
  const float4* xr = (const float4*)(X + (size_t)row * 512);
  float4 a = xr[lane], c = xr[64 + lane];
  float s = a.x + a.y + a.z + a.w + c.x + c.y + c.z + c.w;
  #pragma unroll
  for (int o = 32; o; o >>= 1) s += __shfl_xor(s, o);
  float mu = s * (1.0f / 512.0f);
  float va = (a.x-mu)*(a.x-mu) + (a.y-mu)*(a.y-mu) + (a.z-mu)*(a.z-mu) + (a.w-mu)*(a.w-mu)
           + (c.x-mu)*(c.x-mu) + (c.y-mu)*(c.y-mu) + (c.z-mu)*(c.z-mu) + (c.w-mu)*(c.w-mu);
  #pragma unroll
  for (int o = 32; o; o >>= 1) va += __shfl_xor(va, o);
  float inv = rsqrtf(va * (1.0f / 512.0f) + 1e-5f);
  const float4* gp = (const float4*)G;
  const float4* bp = (const float4*)Bt;
  float4 g0 = gp[lane], g1 = gp[64 + lane], b0 = bp[lane], b1 = bp[64 + lane];
  float4 y0, y1;
  y0.x = (a.x-mu)*inv*g0.x + b0.x; y0.y = (a.y-mu)*inv*g0.y + b0.y;
  y0.z = (a.z-mu)*inv*g0.z + b0.z; y0.w = (a.w-mu)*inv*g0.w + b0.w;
  y1.x = (c.x-mu)*inv*g1.x + b1.x; y1.y = (c.y-mu)*inv*g1.y + b1.y;
  y1.z = (c.z-mu)*inv*g1.z + b1.z; y1.w = (c.w-mu)*inv*g1.w + b1.w;
  float4* op = (float4*)(out + (size_t)row * 512);
  op[lane] = y0; op[64 + lane] = y1;
}

// ---------------- bf16 MFMA GEMM body (128x128 tile, BK=64, 4 waves) ----------------
// MODE 0: bf16 out stride 512. MODE 1: KV split -> k natural + v transposed. MODE 2: f32 out.
template<int MODE>
__device__ __forceinline__ void gemm_body(
    const unsigned short* __restrict__ A, const unsigned short* __restrict__ BT,
    void* __restrict__ out0, void* __restrict__ out1, int bx, int by,
    unsigned short* As, unsigned short* Bs)
{
  const int t = threadIdx.x;
  const int lane = t & 63, l16 = lane & 15, lhi = lane >> 4;
  const int w = t >> 6, wm = w >> 1, wn = w & 1;
  const int rowBase = by * 128;
  const int colBase = bx * 128;

  f32x4 acc[4][4];
  #pragma unroll
  for (int i = 0; i < 4; i++)
    #pragma unroll
    for (int j = 0; j < 4; j++)
      acc[i][j] = f32x4{0.f, 0.f, 0.f, 0.f};

  uint4 ra[4], rb[4];
  auto gload = [&](int kt) {
    #pragma unroll
    for (int i = 0; i < 4; i++) {
      int c = i * 256 + t;
      int rr = c >> 3, cw = c & 7;
      ra[i] = *(const uint4*)(A  + (size_t)(rowBase + rr) * 512 + kt * 64 + cw * 8);
      rb[i] = *(const uint4*)(BT + (size_t)(colBase + rr) * 512 + kt * 64 + cw * 8);
    }
  };
  auto lstore = [&]() {
    #pragma unroll
    for (int i = 0; i < 4; i++) {
      int c = i * 256 + t;
      int rr = c >> 3, cw = c & 7, sz = cw ^ (rr & 7);
      *(uint4*)((char*)As + rr * 128 + sz * 16) = ra[i];
      *(uint4*)((char*)Bs + rr * 128 + sz * 16) = rb[i];
    }
  };

  gload(0);
  for (int kt = 0; kt < 8; ++kt) {
    lstore();
    __syncthreads();
    if (kt < 7) gload(kt + 1);
    #pragma unroll
    for (int ks = 0; ks < 2; ++ks) {
      bf16x8 af[4], bb[4];
      #pragma unroll
      for (int mi = 0; mi < 4; mi++) {
        int rr = wm * 64 + mi * 16 + l16;
        int cc = ks * 4 + lhi;
        af[mi] = *(const bf16x8*)((const char*)As + rr * 128 + ((cc ^ (rr & 7)) * 16));
      }
      #pragma unroll
      for (int ni = 0; ni < 4; ni++) {
        int rr = wn * 64 + ni * 16 + l16;
        int cc = ks * 4 + lhi;
        bb[ni] = *(const bf16x8*)((const char*)Bs + rr * 128 + ((cc ^ (rr & 7)) * 16));
      }
      #pragma unroll
      for (int mi = 0; mi < 4; mi++)
        #pragma unroll
        for (int ni = 0; ni < 4; ni++)
          acc[mi][ni] = MFMA16(af[mi], bb[ni], acc[mi][ni]);
    }
    __syncthreads();
  }

  const int r0 = rowBase + wm * 64 + lhi * 4;
  const int c0 = colBase + wn * 64 + l16;
  #pragma unroll
  for (int mi = 0; mi < 4; mi++) {
    #pragma unroll
    for (int ni = 0; ni < 4; ni++) {
      int row = r0 + mi * 16;
      int col = c0 + ni * 16;
      if constexpr (MODE == 0) {
        #pragma unroll
        for (int r = 0; r < 4; r++)
          ((unsigned short*)out0)[(size_t)(row + r) * 512 + col] = f2bf(acc[mi][ni][r]);
      } else if constexpr (MODE == 1) {
        if (col < 512) {
          #pragma unroll
          for (int r = 0; r < 4; r++)
            ((unsigned short*)out0)[(size_t)(row + r) * 512 + col] = f2bf(acc[mi][ni][r]);
        } else {
          int dfull = col - 512, hh = dfull >> 6, dd = dfull & 63;
          int bb2 = row >> 11, mm = row & 2047;
          ushort4 p = make_ushort4(f2bf(acc[mi][ni][0]), f2bf(acc[mi][ni][1]),
                                   f2bf(acc[mi][ni][2]), f2bf(acc[mi][ni][3]));
          *(ushort4*)((unsigned short*)out1 + ((size_t)((bb2 * 8 + hh) * 64 + dd)) * 2048 + mm) = p;
        }
      } else {
        #pragma unroll
        for (int r = 0; r < 4; r++)
          ((float*)out0)[(size_t)(row + r) * 512 + col] = acc[mi][ni][r];
      }
    }
  }
}

__global__ __launch_bounds__(256) void k_qkv(
    const unsigned short* __restrict__ xn, const unsigned short* __restrict__ WqT,
    unsigned short* __restrict__ qb,
    const unsigned short* __restrict__ cb, const unsigned short* __restrict__ WkvT,
    unsigned short* __restrict__ kb, unsigned short* __restrict__ vT)
{
  __shared__ __align__(16) unsigned short As[128 * 64];
  __shared__ __align__(16) unsigned short Bs[128 * 64];
  int bid = blockIdx.x;
  if (bid < 128) gemm_body<0>(xn, WqT, qb, nullptr, bid & 3, bid >> 2, As, Bs);
  else { int b2 = bid - 128; gemm_body<1>(cb, WkvT, kb, vT, b2 & 7, b2 >> 3, As, Bs); }
}

__global__ __launch_bounds__(256) void k_oproj(
    const unsigned short* __restrict__ ao, const unsigned short* __restrict__ WoT,
    float* __restrict__ proj)
{
  __shared__ __align__(16) unsigned short As[128 * 64];
  __shared__ __align__(16) unsigned short Bs[128 * 64];
  int bid = blockIdx.x;
  gemm_body<2>(ao, WoT, proj, nullptr, bid & 3, bid >> 2, As, Bs);
}

// ---------------- flash attention, swapped-operand 32x32 MFMA, barrier-free KV loop ----------------
// grid (32,16): block = 4 waves = 2 q-tiles x 2 kv-halves. Each wave: 32 q, 1024 kv.
// S = mfma(K,Q): lane holds 16 kv-scores of q=lane&31 (kv=(r&3)+8*(r>>2)+4*hi).
// Softmax in-lane; P->bf16 via cvt_pk + 4 permlane32_swap; PV = mfma(V^T, P) accumulates O^T.
__global__ __launch_bounds__(256, 2) void k_attn(
    const unsigned short* __restrict__ Q, const unsigned short* __restrict__ Kb,
    const unsigned short* __restrict__ VT, const unsigned int* __restrict__ mb,
    unsigned short* __restrict__ O)
{
  __shared__ __align__(16) float mbuf[2][64][36];
  __shared__ float mml[2][64][2];
  const int t = threadIdx.x, lane = t & 63, q5 = lane & 31, hi = lane >> 5;
  const int w = t >> 6, pr = w >> 1, half = w & 1;
  const int bh = blockIdx.y, b = bh >> 3, h = bh & 7;
  const int q0 = (blockIdx.x * 2 + pr) * 32;
  const float C2f = 0.022542110013890053f;   // SCALE^2 * log2(e)

  bf16x8 qf[4];
  {
    const unsigned short* qp = Q + (size_t)(b * 2048 + q0 + q5) * 512 + h * 64 + hi * 8;
    #pragma unroll
    for (int kk = 0; kk < 4; kk++) qf[kk] = *(const bf16x8*)(qp + kk * 16);
  }
  const unsigned short* kp = Kb + (size_t)(b * 2048 + q5) * 512 + h * 64 + hi * 8;
  const unsigned short* vp = VT + ((size_t)bh * 64 + q5) * 2048 + hi * 8;
  const unsigned int* mbp = mb + b * 64;
  const int base = half * 1024;

  float mrun = -3e38f, lrun = 0.f;
  f32x16 acc0, acc1;
  #pragma unroll
  for (int i = 0; i < 16; i++) { acc0[i] = 0.f; acc1[i] = 0.f; }

  bf16x8 kf0[4], vf0[4], kf1[4], vf1[4];
  auto loadK = [&](int j0, bf16x8* kf) {
    #pragma unroll
    for (int kk = 0; kk < 4; kk++) kf[kk] = *(const bf16x8*)(kp + (size_t)j0 * 512 + kk * 16);
  };
  auto loadV = [&](int j0, bf16x8* vf) {
    #pragma unroll
    for (int d2 = 0; d2 < 2; d2++)
      #pragma unroll
      for (int t2 = 0; t2 < 2; t2++)
        vf[d2 * 2 + t2] = *(const bf16x8*)(vp + (size_t)d2 * 32 * 2048 + j0 + t2 * 16);
  };

  auto tile = [&](bf16x8* kf, bf16x8* vf, int j0) {
    f32x16 s;
    #pragma unroll
    for (int i = 0; i < 16; i++) s[i] = 0.f;
    #pragma unroll
    for (int kk = 0; kk < 4; kk++) s = MFMA32(kf[kk], qf[kk], s);

    float m0 = fmaxf(fmaxf(s[0], s[1]),  fmaxf(s[2], s[3]));
    float m1 = fmaxf(fmaxf(s[4], s[5]),  fmaxf(s[6], s[7]));
    float m2 = fmaxf(fmaxf(s[8], s[9]),  fmaxf(s[10], s[11]));
    float m3 = fmaxf(fmaxf(s[12], s[13]), fmaxf(s[14], s[15]));
    float tmax = fmaxf(fmaxf(m0, m1), fmaxf(m2, m3));
    tmax = fmaxf(tmax, __shfl_xor(tmax, 32));
    if (!__all(tmax <= mrun + 400.f)) {       // defer-max: rare
      float mnew = fmaxf(mrun, tmax);
      float sf = fexp2((mrun - mnew) * C2f);
      lrun *= sf;
      #pragma unroll
      for (int i = 0; i < 16; i++) { acc0[i] *= sf; acc1[i] *= sf; }
      mrun = mnew;
    }
    unsigned mh = mbp[j0 >> 5] >> (hi * 4);
    float nb = -mrun * C2f;
    float p[16];
    #pragma unroll
    for (int r = 0; r < 16; r++) {
      float pv = fexp2(fmaf(s[r], C2f, nb));
      p[r] = ((mh >> ((r & 3) + 8 * (r >> 2))) & 1u) ? pv : 0.f;
    }
    float rsa = (p[0] + p[1]) + (p[2] + p[3]);
    float rsb = (p[4] + p[5]) + (p[6] + p[7]);
    float rsc = (p[8] + p[9]) + (p[10] + p[11]);
    float rsd = (p[12] + p[13]) + (p[14] + p[15]);
    float rs = (rsa + rsb) + (rsc + rsd);
    rs += __shfl_xor(rs, 32);
    lrun += rs;

    unsigned wd[8];
    #pragma unroll
    for (int i = 0; i < 8; i++) wd[i] = cvtpk(p[2 * i], p[2 * i + 1]);
    plswap(wd[0], wd[2]); plswap(wd[1], wd[3]);
    plswap(wd[4], wd[6]); plswap(wd[5], wd[7]);
    union { unsigned u[4]; bf16x8 v; } U0, U1;
    U0.u[0] = wd[0]; U0.u[1] = wd[1]; U0.u[2] = wd[2]; U0.u[3] = wd[3];
    U1.u[0] = wd[4]; U1.u[1] = wd[5]; U1.u[2] = wd[6]; U1.u[3] = wd[7];

    acc0 = MFMA32(vf[0], U0.v, acc0);   // dblk0, kv 0..15
    acc0 = MFMA32(vf[1], U1.v, acc0);   // dblk0, kv 16..31
    acc1 = MFMA32(vf[2], U0.v, acc1);   // dblk1
    acc1 = MFMA32(vf[3], U1.v, acc1);
  };

  loadK(base, kf0); loadV(base, vf0);
  for (int it = 0; it < 16; ++it) {
    int j0 = base + it * 64;
    loadK(j0 + 32, kf1); loadV(j0 + 32, vf1);
    tile(kf0, vf0, j0);
    loadK(j0 + 64, kf0); loadV(j0 + 64, vf0);   // last iter overreads into ws scratch (unused)
    tile(kf1, vf1, j0 + 32);
  }

  // ---- merge the two kv-halves of this q-tile ----
  if (half) {
    #pragma unroll
    for (int i = 0; i < 16; i++) { mbuf[pr][lane][i] = acc0[i]; mbuf[pr][lane][16 + i] = acc1[i]; }
    mml[pr][lane][0] = mrun; mml[pr][lane][1] = lrun;
  }
  __syncthreads();
  if (!half) {
    float m1v = mml[pr][lane][0], l1v = mml[pr][lane][1];
    float mN = fmaxf(mrun, m1v);
    float s0 = fexp2((mrun - mN) * C2f), s1 = fexp2((m1v - mN) * C2f);
    float linv = 1.f / (lrun * s0 + l1v * s1);
    float a2[32];
    #pragma unroll
    for (int i = 0; i < 16; i++) {
      a2[i]      = (acc0[i] * s0 + mbuf[pr][lane][i] * s1) * linv;
      a2[16 + i] = (acc1[i] * s0 + mbuf[pr][lane][16 + i] * s1) * linv;
    }
    // transpose O^T[d][q] -> O[q][d] via per-wave LDS (stride 72 shorts, 16B-aligned rows)
    unsigned short* ot = (unsigned short*)&mbuf[pr][0][0];
    #pragma unroll
    for (int d2 = 0; d2 < 2; d2++)
      #pragma unroll
      for (int i = 0; i < 8; i++) {
        int d0 = ((2 * i) & 3) + 8 * (i >> 1) + 4 * hi + 32 * d2;
        unsigned wv = cvtpk(a2[d2 * 16 + 2 * i], a2[d2 * 16 + 2 * i + 1]);
        *(unsigned*)(ot + q5 * 72 + d0) = wv;
      }
    #pragma unroll
    for (int it2 = 0; it2 < 4; ++it2) {
      int row = (lane >> 3) + it2 * 8, ch = lane & 7;
      uint4 val = *(const uint4*)(ot + row * 72 + ch * 8);
      *(uint4*)(O + ((size_t)(b * 2048 + q0 + row)) * 512 + h * 64 + ch * 8) = val;
    }
  }
}

// ---------------- host ----------------
extern "C" void kernel_launch(void* const* d_in, const int* in_sizes, int n_in,
                              void* d_out, int out_size, void* d_ws, size_t ws_size,
                              hipStream_t stream) {
  const float* x     = (const float*)d_in[0];
  const float* ctx   = (const float*)d_in[1];
  const int*   mask  = (const int*)d_in[2];
  const float* ln_g  = (const float*)d_in[3];
  const float* ln_b  = (const float*)d_in[4];
  const float* Wq    = (const float*)d_in[5];
  const float* Wkv   = (const float*)d_in[6];
  const float* Wo    = (const float*)d_in[7];
  const float* lno_g = (const float*)d_in[8];
  const float* lno_b = (const float*)d_in[9];
  float* out = (float*)d_out;

  char* ws = (char*)d_ws;
  unsigned short* WqT  = (unsigned short*)(ws + 0);                         // 512 KB
  unsigned short* WkvT = (unsigned short*)(ws + (size_t)1 * (1 << 19));     // 1 MB
  unsigned short* WoT  = (unsigned short*)(ws + (size_t)3 * (1 << 19));     // 512 KB
  unsigned short* xn   = (unsigned short*)(ws + (size_t)2  * (1 << 20));    // 4 MB
  unsigned short* cb   = (unsigned short*)(ws + (size_t)6  * (1 << 20));    // 4 MB
  unsigned short* qb   = (unsigned short*)(ws + (size_t)10 * (1 << 20));    // 4 MB
  unsigned short* kb   = (unsigned short*)(ws + (size_t)14 * (1 << 20));    // 4 MB
  unsigned short* vT   = (unsigned short*)(ws + (size_t)18 * (1 << 20));    // 4 MB
  unsigned short* ao   = (unsigned short*)(ws + (size_t)22 * (1 << 20));    // 4 MB
  float* proj          = (float*)(ws + (size_t)26 * (1 << 20));             // 8 MB
  unsigned int* mbw    = (unsigned int*)(ws + (size_t)26 * (1 << 20));      // 512B, overlaps proj (dead by then)

  k_prep<<<4112, 256, 0, stream>>>(Wq, Wkv, Wo, x, ln_g, ln_b, ctx, mask,
                                   WqT, WkvT, WoT, xn, cb, mbw);
  k_qkv<<<384, 256, 0, stream>>>(xn, WqT, qb, cb, WkvT, kb, vT);
  k_attn<<<dim3(32, 16), 256, 0, stream>>>(qb, kb, vT, mbw, ao);
  k_oproj<<<128, 256, 0, stream>>>(ao, WoT, proj);
  k_layernorm_f<<<1024, 256, 0, stream>>>(proj, lno_g, lno_b, out);
}

// Round 3
// 139.692 us; speedup vs baseline: 1.4126x; 1.0396x over previous
//
#include <hip/hip_runtime.h>
#include <stdint.h>

typedef float f32x4 __attribute__((ext_vector_type(4)));
typedef float f32x16 __attribute__((ext_vector_type(16)));
typedef __bf16 bf16x8 __attribute__((ext_vector_type(8)));
typedef unsigned int uint2v __attribute__((ext_vector_type(2)));

#define MFMA16(a,b,c) __builtin_amdgcn_mfma_f32_16x16x32_bf16((a),(b),(c),0,0,0)
#define MFMA32(a,b,c) __builtin_amdgcn_mfma_f32_32x32x16_bf16((a),(b),(c),0,0,0)

__device__ __forceinline__ unsigned short f2bf(float f){
  unsigned int u = __float_as_uint(f);
  u += 0x7FFFu + ((u >> 16) & 1u);
  return (unsigned short)(u >> 16);
}

__device__ __forceinline__ unsigned cvtpk(float lo, float hi){
  unsigned r;
  asm volatile("v_cvt_pk_bf16_f32 %0, %1, %2" : "=v"(r) : "v"(lo), "v"(hi));
  return r;
}

__device__ __forceinline__ float fexp2(float x){
#if __has_builtin(__builtin_amdgcn_exp2f)
  return __builtin_amdgcn_exp2f(x);
#else
  return exp2f(x);
#endif
}

__device__ __forceinline__ void plswap(unsigned &a, unsigned &b){
#if __has_builtin(__builtin_amdgcn_permlane32_swap)
  uint2v r = __builtin_amdgcn_permlane32_swap(a, b, false, false);
  a = r[0]; b = r[1];
#else
  unsigned xa = __shfl_xor(a, 32), xb = __shfl_xor(b, 32);
  int hi = (threadIdx.x & 63) >> 5;
  unsigned na = hi ? xb : a;
  unsigned nb = hi ? b : xa;
  a = na; b = nb;
#endif
}

// ---------------- prep router: weight transposes + LN(x) + cast(ctx) + maskbits ----------------
__global__ __launch_bounds__(256) void k_prep(
    const float* __restrict__ Wq, const float* __restrict__ Wkv, const float* __restrict__ Wo,
    const float* __restrict__ x, const float* __restrict__ ln_g, const float* __restrict__ ln_b,
    const float* __restrict__ ctx, const int* __restrict__ mask,
    unsigned short* __restrict__ WqT, unsigned short* __restrict__ WkvT, unsigned short* __restrict__ WoT,
    unsigned short* __restrict__ xn, unsigned short* __restrict__ cb, unsigned int* __restrict__ mb)
{
  __shared__ float tile[32][33];
  const int bid = blockIdx.x, t = threadIdx.x;
  if (bid < 1024) {
    const float* W; unsigned short* WT; int N, bx, by;
    if (bid < 256)      { W = Wq;  WT = WqT;  N = 512;  bx = bid & 15;        by = bid >> 4; }
    else if (bid < 768) { W = Wkv; WT = WkvT; N = 1024; bx = (bid-256) & 31;  by = (bid-256) >> 5; }
    else                { W = Wo;  WT = WoT;  N = 512;  bx = (bid-768) & 15;  by = (bid-768) >> 4; }
    const int tx = t & 31, ty = t >> 5;
    #pragma unroll
    for (int i = 0; i < 4; i++)
      tile[ty + i*8][tx] = W[(size_t)(by*32 + ty + i*8) * N + bx*32 + tx];
    __syncthreads();
    #pragma unroll
    for (int i = 0; i < 4; i++)
      WT[(size_t)(bx*32 + ty + i*8) * 512 + by*32 + tx] = f2bf(tile[tx][ty + i*8]);
  } else if (bid < 2048) {
    int row = (bid - 1024) * 4 + (t >> 6);
    int lane = t & 63;
    const float4* xr = (const float4*)(x + (size_t)row * 512);
    float4 a = xr[lane], c = xr[64 + lane];
    float s = a.x + a.y + a.z + a.w + c.x + c.y + c.z + c.w;
    #pragma unroll
    for (int o = 32; o; o >>= 1) s += __shfl_xor(s, o);
    float mu = s * (1.0f / 512.0f);
    float va = (a.x-mu)*(a.x-mu) + (a.y-mu)*(a.y-mu) + (a.z-mu)*(a.z-mu) + (a.w-mu)*(a.w-mu)
             + (c.x-mu)*(c.x-mu) + (c.y-mu)*(c.y-mu) + (c.z-mu)*(c.z-mu) + (c.w-mu)*(c.w-mu);
    #pragma unroll
    for (int o = 32; o; o >>= 1) va += __shfl_xor(va, o);
    float inv = rsqrtf(va * (1.0f / 512.0f) + 1e-5f);
    const float4* gp = (const float4*)ln_g;
    const float4* bp = (const float4*)ln_b;
    float4 g0 = gp[lane], g1 = gp[64 + lane], b0 = bp[lane], b1 = bp[64 + lane];
    ushort4* op = (ushort4*)(xn + (size_t)row * 512);
    op[lane]      = make_ushort4(f2bf((a.x-mu)*inv*g0.x + b0.x), f2bf((a.y-mu)*inv*g0.y + b0.y),
                                 f2bf((a.z-mu)*inv*g0.z + b0.z), f2bf((a.w-mu)*inv*g0.w + b0.w));
    op[64 + lane] = make_ushort4(f2bf((c.x-mu)*inv*g1.x + b1.x), f2bf((c.y-mu)*inv*g1.y + b1.y),
                                 f2bf((c.z-mu)*inv*g1.z + b1.z), f2bf((c.w-mu)*inv*g1.w + b1.w));
  } else if (bid < 4096) {
    int i = (bid - 2048) * 256 + t;
    float4 v = ((const float4*)ctx)[i];
    ((ushort4*)cb)[i] = make_ushort4(f2bf(v.x), f2bf(v.y), f2bf(v.z), f2bf(v.w));
  } else {
    int g = (bid - 4096) * 4 + (t >> 6);
    int ln = t & 63;
    int v = mask[g * 64 + ln];
    unsigned long long bb = __ballot(v != 0);
    if (ln == 0) { mb[g*2] = (unsigned)bb; mb[g*2+1] = (unsigned)(bb >> 32); }
  }
}

// ---------------- final layernorm (f32 in/out) ----------------
__global__ __launch_bounds__(256) void k_layernorm_f(
    const float* __restrict__ X, const float* __restrict__ G,
    const float* __restrict__ Bt, float* __restrict__ out)
{
  int row = blockIdx.x * 4 + (threadIdx.x >> 6);
  int lane = threadIdx.x & 63;
  const float4* xr = (const float4*)(X + (size_t)row * 512);
  float4 a = xr[lane], c = xr[64 + lane];
  float s = a.x + a.y + a.z + a.w + c.x + c.y + c.z + c.w;
  #pragma unroll
  for (int o = 32; o; o >>= 1) s += __shfl_xor(s, o);
  float mu = s * (1.0f / 512.0f);
  float va = (a.x-mu)*(a.x-mu) + (a.y-mu)*(a.y-mu) + (a.z-mu)*(a.z-mu) + (a.w-mu)*(a.w-mu)
           + (c.x-mu)*(c.x-mu) + (c.y-mu)*(c.y-mu) + (c.z-mu)*(c.z-mu) + (c.w-mu)*(c.w-mu);
  #pragma unroll
  for (int o = 32; o; o >>= 1) va += __shfl_xor(va, o);
  float inv = rsqrtf(va * (1.0f / 512.0f) + 1e-5f);
  const float4* gp = (const float4*)G;
  const float4* bp = (const float4*)Bt;
  float4 g0 = gp[lane], g1 = gp[64 + lane], b0 = bp[lane], b1 = bp[64 + lane];
  float4 y0, y1;
  y0.x = (a.x-mu)*inv*g0.x + b0.x; y0.y = (a.y-mu)*inv*g0.y + b0.y;
  y0.z = (a.z-mu)*inv*g0.z + b0.z; y0.w = (a.w-mu)*inv*g0.w + b0.w;
  y1.x = (c.x-mu)*inv*g1.x + b1.x; y1.y = (c.y-mu)*inv*g1.y + b1.y;
  y1.z = (c.z-mu)*inv*g1.z + b1.z; y1.w = (c.w-mu)*inv*g1.w + b1.w;
  float4* op = (float4*)(out + (size_t)row * 512);
  op[lane] = y0; op[64 + lane] = y1;
}

// ---------------- bf16 MFMA GEMM body (128x128 tile, BK=64, 4 waves) ----------------
// MODE 0: bf16 out stride 512. MODE 1: KV -> fragment-packed Kp (out0) + Vp (out1).
// MODE 2: f32 out stride 512.
// Packed layouts (per bh, tile = kv>>5):
//  Kp: (bh*64+tile)*2048 + (d>>4)*512 + ((kv&31) + 32*((d>>3)&1))*8 + (d&7)
//  Vp: (bh*64+tile)*2048 + (d>>5)*1024 + ((kv>>4)&1)*512 + ((d&31) + 32*((kv>>3)&1))*8 + (kv&7)
template<int MODE>
__device__ __forceinline__ void gemm_body(
    const unsigned short* __restrict__ A, const unsigned short* __restrict__ BT,
    void* __restrict__ out0, void* __restrict__ out1, int bx, int by,
    unsigned short* As, unsigned short* Bs)
{
  const int t = threadIdx.x;
  const int lane = t & 63, l16 = lane & 15, lhi = lane >> 4;
  const int w = t >> 6, wm = w >> 1, wn = w & 1;
  const int rowBase = by * 128;
  const int colBase = bx * 128;

  f32x4 acc[4][4];
  #pragma unroll
  for (int i = 0; i < 4; i++)
    #pragma unroll
    for (int j = 0; j < 4; j++)
      acc[i][j] = f32x4{0.f, 0.f, 0.f, 0.f};

  uint4 ra[4], rb[4];
  auto gload = [&](int kt) {
    #pragma unroll
    for (int i = 0; i < 4; i++) {
      int c = i * 256 + t;
      int rr = c >> 3, cw = c & 7;
      ra[i] = *(const uint4*)(A  + (size_t)(rowBase + rr) * 512 + kt * 64 + cw * 8);
      rb[i] = *(const uint4*)(BT + (size_t)(colBase + rr) * 512 + kt * 64 + cw * 8);
    }
  };
  auto lstore = [&]() {
    #pragma unroll
    for (int i = 0; i < 4; i++) {
      int c = i * 256 + t;
      int rr = c >> 3, cw = c & 7, sz = cw ^ (rr & 7);
      *(uint4*)((char*)As + rr * 128 + sz * 16) = ra[i];
      *(uint4*)((char*)Bs + rr * 128 + sz * 16) = rb[i];
    }
  };

  gload(0);
  for (int kt = 0; kt < 8; ++kt) {
    lstore();
    __syncthreads();
    if (kt < 7) gload(kt + 1);
    #pragma unroll
    for (int ks = 0; ks < 2; ++ks) {
      bf16x8 af[4], bb[4];
      #pragma unroll
      for (int mi = 0; mi < 4; mi++) {
        int rr = wm * 64 + mi * 16 + l16;
        int cc = ks * 4 + lhi;
        af[mi] = *(const bf16x8*)((const char*)As + rr * 128 + ((cc ^ (rr & 7)) * 16));
      }
      #pragma unroll
      for (int ni = 0; ni < 4; ni++) {
        int rr = wn * 64 + ni * 16 + l16;
        int cc = ks * 4 + lhi;
        bb[ni] = *(const bf16x8*)((const char*)Bs + rr * 128 + ((cc ^ (rr & 7)) * 16));
      }
      #pragma unroll
      for (int mi = 0; mi < 4; mi++)
        #pragma unroll
        for (int ni = 0; ni < 4; ni++)
          acc[mi][ni] = MFMA16(af[mi], bb[ni], acc[mi][ni]);
    }
    __syncthreads();
  }

  const int r0 = rowBase + wm * 64 + lhi * 4;
  const int c0 = colBase + wn * 64 + l16;
  #pragma unroll
  for (int mi = 0; mi < 4; mi++) {
    #pragma unroll
    for (int ni = 0; ni < 4; ni++) {
      int row = r0 + mi * 16;
      int col = c0 + ni * 16;
      if constexpr (MODE == 0) {
        #pragma unroll
        for (int r = 0; r < 4; r++)
          ((unsigned short*)out0)[(size_t)(row + r) * 512 + col] = f2bf(acc[mi][ni][r]);
      } else if constexpr (MODE == 1) {
        int bb2 = row >> 11;
        int kv0 = row & 2047;
        if (col < 512) {
          int hh = col >> 6, d = col & 63;
          size_t tb = ((size_t)((bb2 * 8 + hh) * 64 + (kv0 >> 5))) * 2048 + (d >> 4) * 512;
          #pragma unroll
          for (int r = 0; r < 4; r++) {
            int kv = kv0 + r;
            ((unsigned short*)out0)[tb + (((kv & 31) + 32 * ((d >> 3) & 1)) * 8) + (d & 7)]
              = f2bf(acc[mi][ni][r]);
          }
        } else {
          int dfull = col - 512, hh = dfull >> 6, d = dfull & 63;
          size_t fl = ((size_t)((bb2 * 8 + hh) * 64 + (kv0 >> 5))) * 2048
                    + (d >> 5) * 1024 + ((kv0 >> 4) & 1) * 512
                    + ((d & 31) + 32 * ((kv0 >> 3) & 1)) * 8 + (kv0 & 7);
          ushort4 p = make_ushort4(f2bf(acc[mi][ni][0]), f2bf(acc[mi][ni][1]),
                                   f2bf(acc[mi][ni][2]), f2bf(acc[mi][ni][3]));
          *(ushort4*)((unsigned short*)out1 + fl) = p;
        }
      } else {
        #pragma unroll
        for (int r = 0; r < 4; r++)
          ((float*)out0)[(size_t)(row + r) * 512 + col] = acc[mi][ni][r];
      }
    }
  }
}

__global__ __launch_bounds__(256) void k_qkv(
    const unsigned short* __restrict__ xn, const unsigned short* __restrict__ WqT,
    unsigned short* __restrict__ qb,
    const unsigned short* __restrict__ cb, const unsigned short* __restrict__ WkvT,
    unsigned short* __restrict__ Kp, unsigned short* __restrict__ Vp)
{
  __shared__ __align__(16) unsigned short As[128 * 64];
  __shared__ __align__(16) unsigned short Bs[128 * 64];
  int bid = blockIdx.x;
  if (bid < 128) gemm_body<0>(xn, WqT, qb, nullptr, bid & 3, bid >> 2, As, Bs);
  else { int b2 = bid - 128; gemm_body<1>(cb, WkvT, Kp, Vp, b2 & 7, b2 >> 3, As, Bs); }
}

__global__ __launch_bounds__(256) void k_oproj(
    const unsigned short* __restrict__ ao, const unsigned short* __restrict__ WoT,
    float* __restrict__ proj)
{
  __shared__ __align__(16) unsigned short As[128 * 64];
  __shared__ __align__(16) unsigned short Bs[128 * 64];
  int bid = blockIdx.x;
  gemm_body<2>(ao, WoT, proj, nullptr, bid & 3, bid >> 2, As, Bs);
}

// ---------------- flash attention v3 ----------------
// 1024 blocks, 4 waves; XCD-swizzled decode: bh pair per XCD (K/V L2-resident).
// Wave w owns kv quarter [w*512, w*512+512) of one 32-q tile; 16 tiles of 32 kv.
// K/V loaded from fragment-packed layouts: fully coalesced 16B/lane.
// 4-way merge via LDS at the end.
__global__ __launch_bounds__(256, 4) void k_attn(
    const unsigned short* __restrict__ Q, const unsigned short* __restrict__ Kp,
    const unsigned short* __restrict__ Vp, const unsigned int* __restrict__ mb,
    unsigned short* __restrict__ O)
{
  __shared__ __align__(16) float mbuf[3][64][34];   // acc(32) + m + l per lane
  const int t = threadIdx.x, lane = t & 63, q5 = lane & 31, hi = lane >> 5;
  const int w = t >> 6;
  const int bid = blockIdx.x;
  const int bh = (bid & 7) * 2 + (bid >> 9);        // XCD-local bh pair
  const int q0 = ((bid >> 3) & 63) * 32;
  const int b = bh >> 3, h = bh & 7;
  const float C2f = 0.022542110013890053f;          // SCALE^2 * log2(e)

  bf16x8 qf[4];
  {
    const unsigned short* qp = Q + (size_t)(b * 2048 + q0 + q5) * 512 + h * 64 + hi * 8;
    #pragma unroll
    for (int kk = 0; kk < 4; kk++) qf[kk] = *(const bf16x8*)(qp + kk * 16);
  }
  const unsigned short* kpb = Kp + (size_t)bh * 131072 + lane * 8;
  const unsigned short* vpb = Vp + (size_t)bh * 131072 + lane * 8;
  const unsigned int* mbp = mb + b * 64;

  float mrun = -3e38f, lrun = 0.f;
  f32x16 acc0, acc1;
  #pragma unroll
  for (int i = 0; i < 16; i++) { acc0[i] = 0.f; acc1[i] = 0.f; }

  bf16x8 kf0[4], vf0[4], kf1[4], vf1[4];
  auto loadK = [&](int tile, bf16x8* kf) {
    #pragma unroll
    for (int kk = 0; kk < 4; kk++)
      kf[kk] = *(const bf16x8*)(kpb + (size_t)tile * 2048 + kk * 512);
  };
  auto loadV = [&](int tile, bf16x8* vf) {
    #pragma unroll
    for (int i = 0; i < 4; i++)
      vf[i] = *(const bf16x8*)(vpb + (size_t)tile * 2048 + i * 512);
  };

  auto tile_f = [&](bf16x8* kf, bf16x8* vf, int tile) {
    f32x16 s;
    #pragma unroll
    for (int i = 0; i < 16; i++) s[i] = 0.f;
    #pragma unroll
    for (int kk = 0; kk < 4; kk++) s = MFMA32(kf[kk], qf[kk], s);

    float m0 = fmaxf(fmaxf(s[0], s[1]),  fmaxf(s[2], s[3]));
    float m1 = fmaxf(fmaxf(s[4], s[5]),  fmaxf(s[6], s[7]));
    float m2 = fmaxf(fmaxf(s[8], s[9]),  fmaxf(s[10], s[11]));
    float m3 = fmaxf(fmaxf(s[12], s[13]), fmaxf(s[14], s[15]));
    float tmax = fmaxf(fmaxf(m0, m1), fmaxf(m2, m3));
    tmax = fmaxf(tmax, __shfl_xor(tmax, 32));
    if (!__all(tmax <= mrun + 400.f)) {             // defer-max: rare
      float mnew = fmaxf(mrun, tmax);
      float sf = fexp2((mrun - mnew) * C2f);
      lrun *= sf;
      #pragma unroll
      for (int i = 0; i < 16; i++) { acc0[i] *= sf; acc1[i] *= sf; }
      mrun = mnew;
    }
    unsigned mh = mbp[tile] >> (hi * 4);
    float nb = -mrun * C2f;
    float p[16];
    #pragma unroll
    for (int r = 0; r < 16; r++) {
      float pv = fexp2(fmaf(s[r], C2f, nb));
      p[r] = ((mh >> ((r & 3) + 8 * (r >> 2))) & 1u) ? pv : 0.f;
    }
    float rsa = (p[0] + p[1]) + (p[2] + p[3]);
    float rsb = (p[4] + p[5]) + (p[6] + p[7]);
    float rsc = (p[8] + p[9]) + (p[10] + p[11]);
    float rsd = (p[12] + p[13]) + (p[14] + p[15]);
    float rs = (rsa + rsb) + (rsc + rsd);
    rs += __shfl_xor(rs, 32);
    lrun += rs;

    unsigned wd[8];
    #pragma unroll
    for (int i = 0; i < 8; i++) wd[i] = cvtpk(p[2 * i], p[2 * i + 1]);
    plswap(wd[0], wd[2]); plswap(wd[1], wd[3]);
    plswap(wd[4], wd[6]); plswap(wd[5], wd[7]);
    union { unsigned u[4]; bf16x8 v; } U0, U1;
    U0.u[0] = wd[0]; U0.u[1] = wd[1]; U0.u[2] = wd[2]; U0.u[3] = wd[3];
    U1.u[0] = wd[4]; U1.u[1] = wd[5]; U1.u[2] = wd[6]; U1.u[3] = wd[7];

    acc0 = MFMA32(vf[0], U0.v, acc0);
    acc0 = MFMA32(vf[1], U1.v, acc0);
    acc1 = MFMA32(vf[2], U0.v, acc1);
    acc1 = MFMA32(vf[3], U1.v, acc1);
  };

  const int tb = w * 16;
  loadK(tb, kf0); loadV(tb, vf0);
  for (int it = 0; it < 8; ++it) {
    int ti = tb + it * 2;
    loadK(ti + 1, kf1); loadV(ti + 1, vf1);
    tile_f(kf0, vf0, ti);
    loadK(ti + 2, kf0); loadV(ti + 2, vf0);   // last iter overreads into adjacent ws buffer (discarded)
    tile_f(kf1, vf1, ti + 1);
  }

  // ---- 4-way merge ----
  if (w) {
    #pragma unroll
    for (int i = 0; i < 16; i++) { mbuf[w-1][lane][i] = acc0[i]; mbuf[w-1][lane][16 + i] = acc1[i]; }
    mbuf[w-1][lane][32] = mrun; mbuf[w-1][lane][33] = lrun;
  }
  __syncthreads();
  if (!w) {
    float mo[3], lo[3];
    #pragma unroll
    for (int wv = 0; wv < 3; wv++) { mo[wv] = mbuf[wv][lane][32]; lo[wv] = mbuf[wv][lane][33]; }
    float mN = fmaxf(fmaxf(mrun, mo[0]), fmaxf(mo[1], mo[2]));
    float sf0 = fexp2((mrun - mN) * C2f);
    float sfv[3];
    float lsum = lrun * sf0;
    #pragma unroll
    for (int wv = 0; wv < 3; wv++) { sfv[wv] = fexp2((mo[wv] - mN) * C2f); lsum += lo[wv] * sfv[wv]; }
    float linv = 1.f / lsum;
    float a2[32];
    #pragma unroll
    for (int i = 0; i < 16; i++) {
      float v0 = acc0[i] * sf0, v1 = acc1[i] * sf0;
      #pragma unroll
      for (int wv = 0; wv < 3; wv++) {
        v0 += mbuf[wv][lane][i] * sfv[wv];
        v1 += mbuf[wv][lane][16 + i] * sfv[wv];
      }
      a2[i] = v0 * linv;
      a2[16 + i] = v1 * linv;
    }
    // transpose O^T[d][q] -> O[q][d] via LDS (stride 72 shorts, 16B-aligned rows)
    unsigned short* ot = (unsigned short*)&mbuf[0][0][0];
    #pragma unroll
    for (int d2 = 0; d2 < 2; d2++)
      #pragma unroll
      for (int i = 0; i < 8; i++) {
        int d0 = ((2 * i) & 3) + 8 * (i >> 1) + 4 * hi + 32 * d2;
        unsigned wv2 = cvtpk(a2[d2 * 16 + 2 * i], a2[d2 * 16 + 2 * i + 1]);
        *(unsigned*)(ot + q5 * 72 + d0) = wv2;
      }
    #pragma unroll
    for (int it2 = 0; it2 < 4; ++it2) {
      int row = (lane >> 3) + it2 * 8, ch = lane & 7;
      uint4 val = *(const uint4*)(ot + row * 72 + ch * 8);
      *(uint4*)(O + ((size_t)(b * 2048 + q0 + row)) * 512 + h * 64 + ch * 8) = val;
    }
  }
}

// ---------------- host ----------------
extern "C" void kernel_launch(void* const* d_in, const int* in_sizes, int n_in,
                              void* d_out, int out_size, void* d_ws, size_t ws_size,
                              hipStream_t stream) {
  const float* x     = (const float*)d_in[0];
  const float* ctx   = (const float*)d_in[1];
  const int*   mask  = (const int*)d_in[2];
  const float* ln_g  = (const float*)d_in[3];
  const float* ln_b  = (const float*)d_in[4];
  const float* Wq    = (const float*)d_in[5];
  const float* Wkv   = (const float*)d_in[6];
  const float* Wo    = (const float*)d_in[7];
  const float* lno_g = (const float*)d_in[8];
  const float* lno_b = (const float*)d_in[9];
  float* out = (float*)d_out;

  char* ws = (char*)d_ws;
  unsigned short* WqT  = (unsigned short*)(ws + 0);                         // 512 KB
  unsigned short* WkvT = (unsigned short*)(ws + (size_t)1 * (1 << 19));     // 1 MB
  unsigned short* WoT  = (unsigned short*)(ws + (size_t)3 * (1 << 19));     // 512 KB
  unsigned short* xn   = (unsigned short*)(ws + (size_t)2  * (1 << 20));    // 4 MB
  unsigned short* cb   = (unsigned short*)(ws + (size_t)6  * (1 << 20));    // 4 MB
  unsigned short* qb   = (unsigned short*)(ws + (size_t)10 * (1 << 20));    // 4 MB
  unsigned short* Kp   = (unsigned short*)(ws + (size_t)14 * (1 << 20));    // 4 MB (fragment-packed)
  unsigned short* Vp   = (unsigned short*)(ws + (size_t)18 * (1 << 20));    // 4 MB (fragment-packed)
  unsigned short* ao   = (unsigned short*)(ws + (size_t)22 * (1 << 20));    // 4 MB
  float* proj          = (float*)(ws + (size_t)26 * (1 << 20));             // 8 MB
  unsigned int* mbw    = (unsigned int*)(ws + (size_t)26 * (1 << 20));      // 512 B, overlaps proj (dead by then)

  k_prep<<<4112, 256, 0, stream>>>(Wq, Wkv, Wo, x, ln_g, ln_b, ctx, mask,
                                   WqT, WkvT, WoT, xn, cb, mbw);
  k_qkv<<<384, 256, 0, stream>>>(xn, WqT, qb, cb, WkvT, Kp, Vp);
  k_attn<<<1024, 256, 0, stream>>>(qb, Kp, Vp, mbw, ao);
  k_oproj<<<128, 256, 0, stream>>>(ao, WoT, proj);
  k_layernorm_f<<<1024, 256, 0, stream>>>(proj, lno_g, lno_b, out);
}

// Round 4
// 107.978 us; speedup vs baseline: 1.8275x; 1.2937x over previous
//
#include <hip/hip_runtime.h>
#include <stdint.h>

typedef float f32x4 __attribute__((ext_vector_type(4)));
typedef float f32x16 __attribute__((ext_vector_type(16)));
typedef __bf16 bf16x8 __attribute__((ext_vector_type(8)));
typedef unsigned int uint2v __attribute__((ext_vector_type(2)));

#define MFMA16(a,b,c) __builtin_amdgcn_mfma_f32_16x16x32_bf16((a),(b),(c),0,0,0)
#define MFMA32(a,b,c) __builtin_amdgcn_mfma_f32_32x32x16_bf16((a),(b),(c),0,0,0)

__device__ __forceinline__ unsigned short f2bf(float f){
  unsigned int u = __float_as_uint(f);
  u += 0x7FFFu + ((u >> 16) & 1u);
  return (unsigned short)(u >> 16);
}

__device__ __forceinline__ unsigned cvtpk(float lo, float hi){
  unsigned r;
  asm volatile("v_cvt_pk_bf16_f32 %0, %1, %2" : "=v"(r) : "v"(lo), "v"(hi));
  return r;
}

__device__ __forceinline__ float fexp2(float x){
#if __has_builtin(__builtin_amdgcn_exp2f)
  return __builtin_amdgcn_exp2f(x);
#else
  return exp2f(x);
#endif
}

__device__ __forceinline__ void plswap(unsigned &a, unsigned &b){
#if __has_builtin(__builtin_amdgcn_permlane32_swap)
  uint2v r = __builtin_amdgcn_permlane32_swap(a, b, false, false);
  a = r[0]; b = r[1];
#else
  unsigned xa = __shfl_xor(a, 32), xb = __shfl_xor(b, 32);
  int hi = (threadIdx.x & 63) >> 5;
  unsigned na = hi ? xb : a;
  unsigned nb = hi ? b : xa;
  a = na; b = nb;
#endif
}

// ---------------- prep router: weight transposes + LN(x) + cast(ctx) + maskbits ----------------
__global__ __launch_bounds__(256) void k_prep(
    const float* __restrict__ Wq, const float* __restrict__ Wkv, const float* __restrict__ Wo,
    const float* __restrict__ x, const float* __restrict__ ln_g, const float* __restrict__ ln_b,
    const float* __restrict__ ctx, const int* __restrict__ mask,
    unsigned short* __restrict__ WqT, unsigned short* __restrict__ WkvT, unsigned short* __restrict__ WoT,
    unsigned short* __restrict__ xn, unsigned short* __restrict__ cb, unsigned int* __restrict__ mb)
{
  __shared__ float tile[32][33];
  const int bid = blockIdx.x, t = threadIdx.x;
  if (bid < 1024) {
    const float* W; unsigned short* WT; int N, bx, by;
    if (bid < 256)      { W = Wq;  WT = WqT;  N = 512;  bx = bid & 15;        by = bid >> 4; }
    else if (bid < 768) { W = Wkv; WT = WkvT; N = 1024; bx = (bid-256) & 31;  by = (bid-256) >> 5; }
    else                { W = Wo;  WT = WoT;  N = 512;  bx = (bid-768) & 15;  by = (bid-768) >> 4; }
    const int tx = t & 31, ty = t >> 5;
    #pragma unroll
    for (int i = 0; i < 4; i++)
      tile[ty + i*8][tx] = W[(size_t)(by*32 + ty + i*8) * N + bx*32 + tx];
    __syncthreads();
    #pragma unroll
    for (int i = 0; i < 4; i++)
      WT[(size_t)(bx*32 + ty + i*8) * 512 + by*32 + tx] = f2bf(tile[tx][ty + i*8]);
  } else if (bid < 2048) {
    int row = (bid - 1024) * 4 + (t >> 6);
    int lane = t & 63;
    const float4* xr = (const float4*)(x + (size_t)row * 512);
    float4 a = xr[lane], c = xr[64 + lane];
    float s = a.x + a.y + a.z + a.w + c.x + c.y + c.z + c.w;
    #pragma unroll
    for (int o = 32; o; o >>= 1) s += __shfl_xor(s, o);
    float mu = s * (1.0f / 512.0f);
    float va = (a.x-mu)*(a.x-mu) + (a.y-mu)*(a.y-mu) + (a.z-mu)*(a.z-mu) + (a.w-mu)*(a.w-mu)
             + (c.x-mu)*(c.x-mu) + (c.y-mu)*(c.y-mu) + (c.z-mu)*(c.z-mu) + (c.w-mu)*(c.w-mu);
    #pragma unroll
    for (int o = 32; o; o >>= 1) va += __shfl_xor(va, o);
    float inv = rsqrtf(va * (1.0f / 512.0f) + 1e-5f);
    const float4* gp = (const float4*)ln_g;
    const float4* bp = (const float4*)ln_b;
    float4 g0 = gp[lane], g1 = gp[64 + lane], b0 = bp[lane], b1 = bp[64 + lane];
    ushort4* op = (ushort4*)(xn + (size_t)row * 512);
    op[lane]      = make_ushort4(f2bf((a.x-mu)*inv*g0.x + b0.x), f2bf((a.y-mu)*inv*g0.y + b0.y),
                                 f2bf((a.z-mu)*inv*g0.z + b0.z), f2bf((a.w-mu)*inv*g0.w + b0.w));
    op[64 + lane] = make_ushort4(f2bf((c.x-mu)*inv*g1.x + b1.x), f2bf((c.y-mu)*inv*g1.y + b1.y),
                                 f2bf((c.z-mu)*inv*g1.z + b1.z), f2bf((c.w-mu)*inv*g1.w + b1.w));
  } else if (bid < 4096) {
    int i = (bid - 2048) * 256 + t;
    float4 v = ((const float4*)ctx)[i];
    ((ushort4*)cb)[i] = make_ushort4(f2bf(v.x), f2bf(v.y), f2bf(v.z), f2bf(v.w));
  } else {
    int g = (bid - 4096) * 4 + (t >> 6);
    int ln = t & 63;
    int v = mask[g * 64 + ln];
    unsigned long long bb = __ballot(v != 0);
    if (ln == 0) { mb[g*2] = (unsigned)bb; mb[g*2+1] = (unsigned)(bb >> 32); }
  }
}

// ---------------- final layernorm (f32 in/out) ----------------
__global__ __launch_bounds__(256) void k_layernorm_f(
    const float* __restrict__ X, const float* __restrict__ G,
    const float* __restrict__ Bt, float* __restrict__ out)
{
  int row = blockIdx.x * 4 + (threadIdx.x >> 6);
  int lane = threadIdx.x & 63;
  const float4* xr = (const float4*)(X + (size_t)row * 512);
  float4 a = xr[lane], c = xr[64 + lane];
  float s = a.x + a.y + a.z + a.w + c.x + c.y + c.z + c.w;
  #pragma unroll
  for (int o = 32; o; o >>= 1) s += __shfl_xor(s, o);
  float mu = s * (1.0f / 512.0f);
  float va = (a.x-mu)*(a.x-mu) + (a.y-mu)*(a.y-mu) + (a.z-mu)*(a.z-mu) + (a.w-mu)*(a.w-mu)
           + (c.x-mu)*(c.x-mu) + (c.y-mu)*(c.y-mu) + (c.z-mu)*(c.z-mu) + (c.w-mu)*(c.w-mu);
  #pragma unroll
  for (int o = 32; o; o >>= 1) va += __shfl_xor(va, o);
  float inv = rsqrtf(va * (1.0f / 512.0f) + 1e-5f);
  const float4* gp = (const float4*)G;
  const float4* bp = (const float4*)Bt;
  float4 g0 = gp[lane], g1 = gp[64 + lane], b0 = bp[lane], b1 = bp[64 + lane];
  float4 y0, y1;
  y0.x = (a.x-mu)*inv*g0.x + b0.x; y0.y = (a.y-mu)*inv*g0.y + b0.y;
  y0.z = (a.z-mu)*inv*g0.z + b0.z; y0.w = (a.w-mu)*inv*g0.w + b0.w;
  y1.x = (c.x-mu)*inv*g1.x + b1.x; y1.y = (c.y-mu)*inv*g1.y + b1.y;
  y1.z = (c.z-mu)*inv*g1.z + b1.z; y1.w = (c.w-mu)*inv*g1.w + b1.w;
  float4* op = (float4*)(out + (size_t)row * 512);
  op[lane] = y0; op[64 + lane] = y1;
}

// ---------------- bf16 MFMA GEMM body (128x128 tile, BK=64, 4 waves) ----------------
// MODE 0: fragment-packed Q out (same packing as Kp, q in place of kv).
// MODE 1: KV -> fragment-packed Kp (out0) + Vp (out1).
// MODE 2: f32 out stride 512.
// Packed layouts (per bh, tile = idx>>5):
//  Kp/Qp: (bh*64+tile)*2048 + (d>>4)*512 + ((i&31) + 32*((d>>3)&1))*8 + (d&7)
//  Vp:    (bh*64+tile)*2048 + (d>>5)*1024 + ((kv>>4)&1)*512 + ((d&31) + 32*((kv>>3)&1))*8 + (kv&7)
template<int MODE>
__device__ __forceinline__ void gemm_body(
    const unsigned short* __restrict__ A, const unsigned short* __restrict__ BT,
    void* __restrict__ out0, void* __restrict__ out1, int bx, int by,
    unsigned short* As, unsigned short* Bs)
{
  const int t = threadIdx.x;
  const int lane = t & 63, l16 = lane & 15, lhi = lane >> 4;
  const int w = t >> 6, wm = w >> 1, wn = w & 1;
  const int rowBase = by * 128;
  const int colBase = bx * 128;

  f32x4 acc[4][4];
  #pragma unroll
  for (int i = 0; i < 4; i++)
    #pragma unroll
    for (int j = 0; j < 4; j++)
      acc[i][j] = f32x4{0.f, 0.f, 0.f, 0.f};

  uint4 ra[4], rb[4];
  auto gload = [&](int kt) {
    #pragma unroll
    for (int i = 0; i < 4; i++) {
      int c = i * 256 + t;
      int rr = c >> 3, cw = c & 7;
      ra[i] = *(const uint4*)(A  + (size_t)(rowBase + rr) * 512 + kt * 64 + cw * 8);
      rb[i] = *(const uint4*)(BT + (size_t)(colBase + rr) * 512 + kt * 64 + cw * 8);
    }
  };
  auto lstore = [&]() {
    #pragma unroll
    for (int i = 0; i < 4; i++) {
      int c = i * 256 + t;
      int rr = c >> 3, cw = c & 7, sz = cw ^ (rr & 7);
      *(uint4*)((char*)As + rr * 128 + sz * 16) = ra[i];
      *(uint4*)((char*)Bs + rr * 128 + sz * 16) = rb[i];
    }
  };

  gload(0);
  for (int kt = 0; kt < 8; ++kt) {
    lstore();
    __syncthreads();
    if (kt < 7) gload(kt + 1);
    #pragma unroll
    for (int ks = 0; ks < 2; ++ks) {
      bf16x8 af[4], bb[4];
      #pragma unroll
      for (int mi = 0; mi < 4; mi++) {
        int rr = wm * 64 + mi * 16 + l16;
        int cc = ks * 4 + lhi;
        af[mi] = *(const bf16x8*)((const char*)As + rr * 128 + ((cc ^ (rr & 7)) * 16));
      }
      #pragma unroll
      for (int ni = 0; ni < 4; ni++) {
        int rr = wn * 64 + ni * 16 + l16;
        int cc = ks * 4 + lhi;
        bb[ni] = *(const bf16x8*)((const char*)Bs + rr * 128 + ((cc ^ (rr & 7)) * 16));
      }
      #pragma unroll
      for (int mi = 0; mi < 4; mi++)
        #pragma unroll
        for (int ni = 0; ni < 4; ni++)
          acc[mi][ni] = MFMA16(af[mi], bb[ni], acc[mi][ni]);
    }
    __syncthreads();
  }

  const int r0 = rowBase + wm * 64 + lhi * 4;
  const int c0 = colBase + wn * 64 + l16;
  #pragma unroll
  for (int mi = 0; mi < 4; mi++) {
    #pragma unroll
    for (int ni = 0; ni < 4; ni++) {
      int row = r0 + mi * 16;
      int col = c0 + ni * 16;
      if constexpr (MODE == 0) {
        int bb2 = row >> 11;
        int qq0 = row & 2047;
        int hh = col >> 6, d = col & 63;
        size_t tb2 = ((size_t)((bb2 * 8 + hh) * 64 + (qq0 >> 5))) * 2048 + (d >> 4) * 512;
        #pragma unroll
        for (int r = 0; r < 4; r++) {
          int qq = qq0 + r;
          ((unsigned short*)out0)[tb2 + (((qq & 31) + 32 * ((d >> 3) & 1)) * 8) + (d & 7)]
            = f2bf(acc[mi][ni][r]);
        }
      } else if constexpr (MODE == 1) {
        int bb2 = row >> 11;
        int kv0 = row & 2047;
        if (col < 512) {
          int hh = col >> 6, d = col & 63;
          size_t tb2 = ((size_t)((bb2 * 8 + hh) * 64 + (kv0 >> 5))) * 2048 + (d >> 4) * 512;
          #pragma unroll
          for (int r = 0; r < 4; r++) {
            int kv = kv0 + r;
            ((unsigned short*)out0)[tb2 + (((kv & 31) + 32 * ((d >> 3) & 1)) * 8) + (d & 7)]
              = f2bf(acc[mi][ni][r]);
          }
        } else {
          int dfull = col - 512, hh = dfull >> 6, d = dfull & 63;
          size_t fl = ((size_t)((bb2 * 8 + hh) * 64 + (kv0 >> 5))) * 2048
                    + (d >> 5) * 1024 + ((kv0 >> 4) & 1) * 512
                    + ((d & 31) + 32 * ((kv0 >> 3) & 1)) * 8 + (kv0 & 7);
          ushort4 p = make_ushort4(f2bf(acc[mi][ni][0]), f2bf(acc[mi][ni][1]),
                                   f2bf(acc[mi][ni][2]), f2bf(acc[mi][ni][3]));
          *(ushort4*)((unsigned short*)out1 + fl) = p;
        }
      } else {
        #pragma unroll
        for (int r = 0; r < 4; r++)
          ((float*)out0)[(size_t)(row + r) * 512 + col] = acc[mi][ni][r];
      }
    }
  }
}

__global__ __launch_bounds__(256) void k_qkv(
    const unsigned short* __restrict__ xn, const unsigned short* __restrict__ WqT,
    unsigned short* __restrict__ Qp,
    const unsigned short* __restrict__ cb, const unsigned short* __restrict__ WkvT,
    unsigned short* __restrict__ Kp, unsigned short* __restrict__ Vp)
{
  __shared__ __align__(16) unsigned short As[128 * 64];
  __shared__ __align__(16) unsigned short Bs[128 * 64];
  int bid = blockIdx.x;
  if (bid < 128) gemm_body<0>(xn, WqT, Qp, nullptr, bid & 3, bid >> 2, As, Bs);
  else { int b2 = bid - 128; gemm_body<1>(cb, WkvT, Kp, Vp, b2 & 7, b2 >> 3, As, Bs); }
}

__global__ __launch_bounds__(256) void k_oproj(
    const unsigned short* __restrict__ ao, const unsigned short* __restrict__ WoT,
    float* __restrict__ proj)
{
  __shared__ __align__(16) unsigned short As[128 * 64];
  __shared__ __align__(16) unsigned short Bs[128 * 64];
  int bid = blockIdx.x;
  gemm_body<2>(ao, WoT, proj, nullptr, bid & 3, bid >> 2, As, Bs);
}

// ---------------- flash attention v4 ----------------
// 1024 blocks, 4 waves; XCD-swizzled decode. Wave w owns kv quarter [w*512, +512).
// Q/K/V all fragment-packed: every load is a coalesced 16B/lane.
// Single K/V buffer + early-issue prefetch (no spill); launch_bounds(256,3).
__global__ __launch_bounds__(256, 3) void k_attn(
    const unsigned short* __restrict__ Qp, const unsigned short* __restrict__ Kp,
    const unsigned short* __restrict__ Vp, const unsigned int* __restrict__ mb,
    unsigned short* __restrict__ O)
{
  __shared__ __align__(16) float mbuf[3][64][34];   // acc(32) + m + l per lane
  const int t = threadIdx.x, lane = t & 63, q5 = lane & 31, hi = lane >> 5;
  const int w = t >> 6;
  const int bid = blockIdx.x;
  const int bh = (bid & 7) * 2 + (bid >> 9);        // XCD-local bh pair
  const int qt = (bid >> 3) & 63;
  const int q0 = qt * 32;
  const int b = bh >> 3, h = bh & 7;
  const float C2f = 0.022542110013890053f;          // SCALE^2 * log2(e)

  bf16x8 qf[4];
  {
    const unsigned short* qp = Qp + (size_t)(bh * 64 + qt) * 2048 + lane * 8;
    #pragma unroll
    for (int kk = 0; kk < 4; kk++) qf[kk] = *(const bf16x8*)(qp + kk * 512);
  }
  const unsigned short* kpb = Kp + (size_t)bh * 131072 + lane * 8;
  const unsigned short* vpb = Vp + (size_t)bh * 131072 + lane * 8;
  const unsigned int* mbp = mb + b * 64;

  float mrun = -3e38f, lrun = 0.f;
  f32x16 acc0, acc1;
  #pragma unroll
  for (int i = 0; i < 16; i++) { acc0[i] = 0.f; acc1[i] = 0.f; }

  bf16x8 kf[4], vf[4];
  auto loadK = [&](int tile) {
    #pragma unroll
    for (int kk = 0; kk < 4; kk++)
      kf[kk] = *(const bf16x8*)(kpb + (size_t)tile * 2048 + kk * 512);
  };
  auto loadV = [&](int tile) {
    #pragma unroll
    for (int i = 0; i < 4; i++)
      vf[i] = *(const bf16x8*)(vpb + (size_t)tile * 2048 + i * 512);
  };

  const int tb = w * 16;
  loadK(tb); loadV(tb);
  for (int it = 0; it < 16; ++it) {
    const int ti = tb + it;

    // ---- QK^T ----
    f32x16 s;
    #pragma unroll
    for (int i = 0; i < 16; i++) s[i] = 0.f;
    #pragma unroll
    for (int kk = 0; kk < 4; kk++) s = MFMA32(kf[kk], qf[kk], s);
    if (it < 15) loadK(ti + 1);      // kf dead: prefetch next K under softmax+PV

    // ---- online softmax ----
    float m0 = fmaxf(fmaxf(s[0], s[1]),  fmaxf(s[2], s[3]));
    float m1 = fmaxf(fmaxf(s[4], s[5]),  fmaxf(s[6], s[7]));
    float m2 = fmaxf(fmaxf(s[8], s[9]),  fmaxf(s[10], s[11]));
    float m3 = fmaxf(fmaxf(s[12], s[13]), fmaxf(s[14], s[15]));
    float tmax = fmaxf(fmaxf(m0, m1), fmaxf(m2, m3));
    tmax = fmaxf(tmax, __shfl_xor(tmax, 32));
    if (!__all(tmax <= mrun + 400.f)) {             // defer-max: rare
      float mnew = fmaxf(mrun, tmax);
      float sf = fexp2((mrun - mnew) * C2f);
      lrun *= sf;
      #pragma unroll
      for (int i = 0; i < 16; i++) { acc0[i] *= sf; acc1[i] *= sf; }
      mrun = mnew;
    }
    unsigned mh = mbp[ti] >> (hi * 4);
    float nb = -mrun * C2f;
    float p[16];
    #pragma unroll
    for (int r = 0; r < 16; r++) {
      float pv = fexp2(fmaf(s[r], C2f, nb));
      p[r] = ((mh >> ((r & 3) + 8 * (r >> 2))) & 1u) ? pv : 0.f;
    }
    float rsa = (p[0] + p[1]) + (p[2] + p[3]);
    float rsb = (p[4] + p[5]) + (p[6] + p[7]);
    float rsc = (p[8] + p[9]) + (p[10] + p[11]);
    float rsd = (p[12] + p[13]) + (p[14] + p[15]);
    float rs = (rsa + rsb) + (rsc + rsd);
    rs += __shfl_xor(rs, 32);
    lrun += rs;

    unsigned wd[8];
    #pragma unroll
    for (int i = 0; i < 8; i++) wd[i] = cvtpk(p[2 * i], p[2 * i + 1]);
    plswap(wd[0], wd[2]); plswap(wd[1], wd[3]);
    plswap(wd[4], wd[6]); plswap(wd[5], wd[7]);
    union { unsigned u[4]; bf16x8 v; } U0, U1;
    U0.u[0] = wd[0]; U0.u[1] = wd[1]; U0.u[2] = wd[2]; U0.u[3] = wd[3];
    U1.u[0] = wd[4]; U1.u[1] = wd[5]; U1.u[2] = wd[6]; U1.u[3] = wd[7];

    // ---- PV ----
    acc0 = MFMA32(vf[0], U0.v, acc0);
    acc0 = MFMA32(vf[1], U1.v, acc0);
    acc1 = MFMA32(vf[2], U0.v, acc1);
    acc1 = MFMA32(vf[3], U1.v, acc1);
    if (it < 15) loadV(ti + 1);      // vf dead: prefetch next V under next QK+softmax
  }

  // ---- 4-way merge ----
  if (w) {
    #pragma unroll
    for (int i = 0; i < 16; i++) { mbuf[w-1][lane][i] = acc0[i]; mbuf[w-1][lane][16 + i] = acc1[i]; }
    mbuf[w-1][lane][32] = mrun; mbuf[w-1][lane][33] = lrun;
  }
  __syncthreads();
  if (!w) {
    float mo[3], lo[3];
    #pragma unroll
    for (int wv = 0; wv < 3; wv++) { mo[wv] = mbuf[wv][lane][32]; lo[wv] = mbuf[wv][lane][33]; }
    float mN = fmaxf(fmaxf(mrun, mo[0]), fmaxf(mo[1], mo[2]));
    float sf0 = fexp2((mrun - mN) * C2f);
    float sfv[3];
    float lsum = lrun * sf0;
    #pragma unroll
    for (int wv = 0; wv < 3; wv++) { sfv[wv] = fexp2((mo[wv] - mN) * C2f); lsum += lo[wv] * sfv[wv]; }
    float linv = 1.f / lsum;
    float a2[32];
    #pragma unroll
    for (int i = 0; i < 16; i++) {
      float v0 = acc0[i] * sf0, v1 = acc1[i] * sf0;
      #pragma unroll
      for (int wv = 0; wv < 3; wv++) {
        v0 += mbuf[wv][lane][i] * sfv[wv];
        v1 += mbuf[wv][lane][16 + i] * sfv[wv];
      }
      a2[i] = v0 * linv;
      a2[16 + i] = v1 * linv;
    }
    // transpose O^T[d][q] -> O[q][d] via LDS (stride 72 shorts, 16B-aligned rows)
    unsigned short* ot = (unsigned short*)&mbuf[0][0][0];
    #pragma unroll
    for (int d2 = 0; d2 < 2; d2++)
      #pragma unroll
      for (int i = 0; i < 8; i++) {
        int d0 = ((2 * i) & 3) + 8 * (i >> 1) + 4 * hi + 32 * d2;
        unsigned wv2 = cvtpk(a2[d2 * 16 + 2 * i], a2[d2 * 16 + 2 * i + 1]);
        *(unsigned*)(ot + q5 * 72 + d0) = wv2;
      }
    #pragma unroll
    for (int it2 = 0; it2 < 4; ++it2) {
      int row = (lane >> 3) + it2 * 8, ch = lane & 7;
      uint4 val = *(const uint4*)(ot + row * 72 + ch * 8);
      *(uint4*)(O + ((size_t)(b * 2048 + q0 + row)) * 512 + h * 64 + ch * 8) = val;
    }
  }
}

// ---------------- host ----------------
extern "C" void kernel_launch(void* const* d_in, const int* in_sizes, int n_in,
                              void* d_out, int out_size, void* d_ws, size_t ws_size,
                              hipStream_t stream) {
  const float* x     = (const float*)d_in[0];
  const float* ctx   = (const float*)d_in[1];
  const int*   mask  = (const int*)d_in[2];
  const float* ln_g  = (const float*)d_in[3];
  const float* ln_b  = (const float*)d_in[4];
  const float* Wq    = (const float*)d_in[5];
  const float* Wkv   = (const float*)d_in[6];
  const float* Wo    = (const float*)d_in[7];
  const float* lno_g = (const float*)d_in[8];
  const float* lno_b = (const float*)d_in[9];
  float* out = (float*)d_out;

  char* ws = (char*)d_ws;
  unsigned short* WqT  = (unsigned short*)(ws + 0);                         // 512 KB
  unsigned short* WkvT = (unsigned short*)(ws + (size_t)1 * (1 << 19));     // 1 MB
  unsigned short* WoT  = (unsigned short*)(ws + (size_t)3 * (1 << 19));     // 512 KB
  unsigned short* xn   = (unsigned short*)(ws + (size_t)2  * (1 << 20));    // 4 MB
  unsigned short* cb   = (unsigned short*)(ws + (size_t)6  * (1 << 20));    // 4 MB
  unsigned short* Qp   = (unsigned short*)(ws + (size_t)10 * (1 << 20));    // 4 MB (fragment-packed)
  unsigned short* Kp   = (unsigned short*)(ws + (size_t)14 * (1 << 20));    // 4 MB (fragment-packed)
  unsigned short* Vp   = (unsigned short*)(ws + (size_t)18 * (1 << 20));    // 4 MB (fragment-packed)
  unsigned short* ao   = (unsigned short*)(ws + (size_t)22 * (1 << 20));    // 4 MB
  float* proj          = (float*)(ws + (size_t)26 * (1 << 20));             // 8 MB
  unsigned int* mbw    = (unsigned int*)(ws + (size_t)26 * (1 << 20));      // 512 B, overlaps proj (dead by then)

  k_prep<<<4112, 256, 0, stream>>>(Wq, Wkv, Wo, x, ln_g, ln_b, ctx, mask,
                                   WqT, WkvT, WoT, xn, cb, mbw);
  k_qkv<<<384, 256, 0, stream>>>(xn, WqT, Qp, cb, WkvT, Kp, Vp);
  k_attn<<<1024, 256, 0, stream>>>(Qp, Kp, Vp, mbw, ao);
  k_oproj<<<128, 256, 0, stream>>>(ao, WoT, proj);
  k_layernorm_f<<<1024, 256, 0, stream>>>(proj, lno_g, lno_b, out);
}

// Round 5
// 106.885 us; speedup vs baseline: 1.8462x; 1.0102x over previous
//
#include <hip/hip_runtime.h>
#include <stdint.h>

typedef float f32x4 __attribute__((ext_vector_type(4)));
typedef float f32x16 __attribute__((ext_vector_type(16)));
typedef __bf16 bf16x8 __attribute__((ext_vector_type(8)));
typedef unsigned int uint2v __attribute__((ext_vector_type(2)));

#define MFMA16(a,b,c) __builtin_amdgcn_mfma_f32_16x16x32_bf16((a),(b),(c),0,0,0)
#define MFMA32(a,b,c) __builtin_amdgcn_mfma_f32_32x32x16_bf16((a),(b),(c),0,0,0)

__device__ __forceinline__ unsigned short f2bf(float f){
  unsigned int u = __float_as_uint(f);
  u += 0x7FFFu + ((u >> 16) & 1u);
  return (unsigned short)(u >> 16);
}

__device__ __forceinline__ unsigned cvtpk(float lo, float hi){
  unsigned r;
  asm volatile("v_cvt_pk_bf16_f32 %0, %1, %2" : "=v"(r) : "v"(lo), "v"(hi));
  return r;
}

__device__ __forceinline__ float fexp2(float x){
#if __has_builtin(__builtin_amdgcn_exp2f)
  return __builtin_amdgcn_exp2f(x);
#else
  return exp2f(x);
#endif
}

__device__ __forceinline__ void plswap(unsigned &a, unsigned &b){
#if __has_builtin(__builtin_amdgcn_permlane32_swap)
  uint2v r = __builtin_amdgcn_permlane32_swap(a, b, false, false);
  a = r[0]; b = r[1];
#else
  unsigned xa = __shfl_xor(a, 32), xb = __shfl_xor(b, 32);
  int hi = (threadIdx.x & 63) >> 5;
  unsigned na = hi ? xb : a;
  unsigned nb = hi ? b : xa;
  a = na; b = nb;
#endif
}

// ---------------- prep router: weight transposes + LN(x) + cast(ctx) + maskbits ----------------
__global__ __launch_bounds__(256) void k_prep(
    const float* __restrict__ Wq, const float* __restrict__ Wkv, const float* __restrict__ Wo,
    const float* __restrict__ x, const float* __restrict__ ln_g, const float* __restrict__ ln_b,
    const float* __restrict__ ctx, const int* __restrict__ mask,
    unsigned short* __restrict__ WqT, unsigned short* __restrict__ WkvT, unsigned short* __restrict__ WoT,
    unsigned short* __restrict__ xn, unsigned short* __restrict__ cb, unsigned int* __restrict__ mb)
{
  __shared__ float tile[32][33];
  const int bid = blockIdx.x, t = threadIdx.x;
  if (bid < 1024) {
    const float* W; unsigned short* WT; int N, bx, by;
    if (bid < 256)      { W = Wq;  WT = WqT;  N = 512;  bx = bid & 15;        by = bid >> 4; }
    else if (bid < 768) { W = Wkv; WT = WkvT; N = 1024; bx = (bid-256) & 31;  by = (bid-256) >> 5; }
    else                { W = Wo;  WT = WoT;  N = 512;  bx = (bid-768) & 15;  by = (bid-768) >> 4; }
    const int tx = t & 31, ty = t >> 5;
    #pragma unroll
    for (int i = 0; i < 4; i++)
      tile[ty + i*8][tx] = W[(size_t)(by*32 + ty + i*8) * N + bx*32 + tx];
    __syncthreads();
    #pragma unroll
    for (int i = 0; i < 4; i++)
      WT[(size_t)(bx*32 + ty + i*8) * 512 + by*32 + tx] = f2bf(tile[tx][ty + i*8]);
  } else if (bid < 2048) {
    int row = (bid - 1024) * 4 + (t >> 6);
    int lane = t & 63;
    const float4* xr = (const float4*)(x + (size_t)row * 512);
    float4 a = xr[lane], c = xr[64 + lane];
    float s = a.x + a.y + a.z + a.w + c.x + c.y + c.z + c.w;
    #pragma unroll
    for (int o = 32; o; o >>= 1) s += __shfl_xor(s, o);
    float mu = s * (1.0f / 512.0f);
    float va = (a.x-mu)*(a.x-mu) + (a.y-mu)*(a.y-mu) + (a.z-mu)*(a.z-mu) + (a.w-mu)*(a.w-mu)
             + (c.x-mu)*(c.x-mu) + (c.y-mu)*(c.y-mu) + (c.z-mu)*(c.z-mu) + (c.w-mu)*(c.w-mu);
    #pragma unroll
    for (int o = 32; o; o >>= 1) va += __shfl_xor(va, o);
    float inv = rsqrtf(va * (1.0f / 512.0f) + 1e-5f);
    const float4* gp = (const float4*)ln_g;
    const float4* bp = (const float4*)ln_b;
    float4 g0 = gp[lane], g1 = gp[64 + lane], b0 = bp[lane], b1 = bp[64 + lane];
    ushort4* op = (ushort4*)(xn + (size_t)row * 512);
    op[lane]      = make_ushort4(f2bf((a.x-mu)*inv*g0.x + b0.x), f2bf((a.y-mu)*inv*g0.y + b0.y),
                                 f2bf((a.z-mu)*inv*g0.z + b0.z), f2bf((a.w-mu)*inv*g0.w + b0.w));
    op[64 + lane] = make_ushort4(f2bf((c.x-mu)*inv*g1.x + b1.x), f2bf((c.y-mu)*inv*g1.y + b1.y),
                                 f2bf((c.z-mu)*inv*g1.z + b1.z), f2bf((c.w-mu)*inv*g1.w + b1.w));
  } else if (bid < 4096) {
    int i = (bid - 2048) * 256 + t;
    float4 v = ((const float4*)ctx)[i];
    ((ushort4*)cb)[i] = make_ushort4(f2bf(v.x), f2bf(v.y), f2bf(v.z), f2bf(v.w));
  } else {
    int g = (bid - 4096) * 4 + (t >> 6);
    int ln = t & 63;
    int v = mask[g * 64 + ln];
    unsigned long long bb = __ballot(v != 0);
    if (ln == 0) { mb[g*2] = (unsigned)bb; mb[g*2+1] = (unsigned)(bb >> 32); }
  }
}

// ---------------- final layernorm (f32 in/out) ----------------
__global__ __launch_bounds__(256) void k_layernorm_f(
    const float* __restrict__ X, const float* __restrict__ G,
    const float* __restrict__ Bt, float* __restrict__ out)
{
  int row = blockIdx.x * 4 + (threadIdx.x >> 6);
  int lane = threadIdx.x & 63;
  const float4* xr = (const float4*)(X + (size_t)row * 512);
  float4 a = xr[lane], c = xr[64 + lane];
  float s = a.x + a.y + a.z + a.w + c.x + c.y + c.z + c.w;
  #pragma unroll
  for (int o = 32; o; o >>= 1) s += __shfl_xor(s, o);
  float mu = s * (1.0f / 512.0f);
  float va = (a.x-mu)*(a.x-mu) + (a.y-mu)*(a.y-mu) + (a.z-mu)*(a.z-mu) + (a.w-mu)*(a.w-mu)
           + (c.x-mu)*(c.x-mu) + (c.y-mu)*(c.y-mu) + (c.z-mu)*(c.z-mu) + (c.w-mu)*(c.w-mu);
  #pragma unroll
  for (int o = 32; o; o >>= 1) va += __shfl_xor(va, o);
  float inv = rsqrtf(va * (1.0f / 512.0f) + 1e-5f);
  const float4* gp = (const float4*)G;
  const float4* bp = (const float4*)Bt;
  float4 g0 = gp[lane], g1 = gp[64 + lane], b0 = bp[lane], b1 = bp[64 + lane];
  float4 y0, y1;
  y0.x = (a.x-mu)*inv*g0.x + b0.x; y0.y = (a.y-mu)*inv*g0.y + b0.y;
  y0.z = (a.z-mu)*inv*g0.z + b0.z; y0.w = (a.w-mu)*inv*g0.w + b0.w;
  y1.x = (c.x-mu)*inv*g1.x + b1.x; y1.y = (c.y-mu)*inv*g1.y + b1.y;
  y1.z = (c.z-mu)*inv*g1.z + b1.z; y1.w = (c.w-mu)*inv*g1.w + b1.w;
  float4* op = (float4*)(out + (size_t)row * 512);
  op[lane] = y0; op[64 + lane] = y1;
}

// ---------------- bf16 MFMA GEMM body (128x128 tile, BK=64, 4 waves) ----------------
// MODE 0: fragment-packed Q out. MODE 1: KV -> packed Kp (out0, bx<4) / Vp (out1, bx>=4).
// MODE 2: f32 out stride 512.
// Packed layouts (per bh, tile = idx>>5, region = 2048 shorts):
//  Kp/Qp: region*2048 + (d>>4)*512 + ((i&31) + 32*((d>>3)&1))*8 + (d&7)
//  Vp:    region*2048 + (d>>5)*1024 + ((kv>>4)&1)*512 + ((d&31) + 32*((kv>>3)&1))*8 + (kv&7)
// Epilogue: stage packed tile in LDS (scatter is cheap there), then 16B/lane coalesced global.
template<int MODE>
__device__ __forceinline__ void gemm_body(
    const unsigned short* __restrict__ A, const unsigned short* __restrict__ BT,
    void* __restrict__ out0, void* __restrict__ out1, int bx, int by,
    unsigned short* smem)
{
  unsigned short* As = smem;
  unsigned short* Bs = smem + 128 * 64;
  const int t = threadIdx.x;
  const int lane = t & 63, l16 = lane & 15, lhi = lane >> 4;
  const int w = t >> 6, wm = w >> 1, wn = w & 1;
  const int rowBase = by * 128;
  const int colBase = bx * 128;

  f32x4 acc[4][4];
  #pragma unroll
  for (int i = 0; i < 4; i++)
    #pragma unroll
    for (int j = 0; j < 4; j++)
      acc[i][j] = f32x4{0.f, 0.f, 0.f, 0.f};

  uint4 ra[4], rb[4];
  auto gload = [&](int kt) {
    #pragma unroll
    for (int i = 0; i < 4; i++) {
      int c = i * 256 + t;
      int rr = c >> 3, cw = c & 7;
      ra[i] = *(const uint4*)(A  + (size_t)(rowBase + rr) * 512 + kt * 64 + cw * 8);
      rb[i] = *(const uint4*)(BT + (size_t)(colBase + rr) * 512 + kt * 64 + cw * 8);
    }
  };
  auto lstore = [&]() {
    #pragma unroll
    for (int i = 0; i < 4; i++) {
      int c = i * 256 + t;
      int rr = c >> 3, cw = c & 7, sz = cw ^ (rr & 7);
      *(uint4*)((char*)As + rr * 128 + sz * 16) = ra[i];
      *(uint4*)((char*)Bs + rr * 128 + sz * 16) = rb[i];
    }
  };

  gload(0);
  for (int kt = 0; kt < 8; ++kt) {
    lstore();
    __syncthreads();
    if (kt < 7) gload(kt + 1);
    #pragma unroll
    for (int ks = 0; ks < 2; ++ks) {
      bf16x8 af[4], bb[4];
      #pragma unroll
      for (int mi = 0; mi < 4; mi++) {
        int rr = wm * 64 + mi * 16 + l16;
        int cc = ks * 4 + lhi;
        af[mi] = *(const bf16x8*)((const char*)As + rr * 128 + ((cc ^ (rr & 7)) * 16));
      }
      #pragma unroll
      for (int ni = 0; ni < 4; ni++) {
        int rr = wn * 64 + ni * 16 + l16;
        int cc = ks * 4 + lhi;
        bb[ni] = *(const bf16x8*)((const char*)Bs + rr * 128 + ((cc ^ (rr & 7)) * 16));
      }
      #pragma unroll
      for (int mi = 0; mi < 4; mi++)
        #pragma unroll
        for (int ni = 0; ni < 4; ni++)
          acc[mi][ni] = MFMA16(af[mi], bb[ni], acc[mi][ni]);
    }
    __syncthreads();
  }

  if constexpr (MODE == 2) {
    const int r0 = rowBase + wm * 64 + lhi * 4;
    const int c0 = colBase + wn * 64 + l16;
    #pragma unroll
    for (int mi = 0; mi < 4; mi++)
      #pragma unroll
      for (int ni = 0; ni < 4; ni++)
        #pragma unroll
        for (int r = 0; r < 4; r++)
          ((float*)out0)[(size_t)(r0 + mi * 16 + r) * 512 + c0 + ni * 16] = acc[mi][ni][r];
  } else {
    // stage block's 128x128 bf16 tile into LDS in packed order, then coalesced global write
    unsigned short* stg = smem;   // 32 KB, K-loop done with it
    const bool isV = (MODE == 1) && (colBase >= 512);
    if (!isV) {
      #pragma unroll
      for (int mi = 0; mi < 4; mi++) {
        int rl = wm * 64 + mi * 16 + lhi * 4;
        int tl = rl >> 5;
        #pragma unroll
        for (int ni = 0; ni < 4; ni++) {
          int cl = wn * 64 + ni * 16 + l16;
          int hl = cl >> 6, d = cl & 63;
          int rbase = (hl * 4 + tl) * 2048 + (d >> 4) * 512 + 256 * ((d >> 3) & 1) + (d & 7);
          #pragma unroll
          for (int r = 0; r < 4; r++)
            stg[rbase + ((rl + r) & 31) * 8] = f2bf(acc[mi][ni][r]);
        }
      }
    } else {
      #pragma unroll
      for (int mi = 0; mi < 4; mi++) {
        int rl = wm * 64 + mi * 16 + lhi * 4;
        int tl = rl >> 5, kvr = rl & 31;
        #pragma unroll
        for (int ni = 0; ni < 4; ni++) {
          int cl = wn * 64 + ni * 16 + l16;
          int hl = cl >> 6, d = cl & 63;
          int off = (hl * 4 + tl) * 2048 + (d >> 5) * 1024 + ((kvr >> 4) & 1) * 512
                  + ((d & 31) + 32 * ((kvr >> 3) & 1)) * 8 + (kvr & 7);
          ushort4 p = make_ushort4(f2bf(acc[mi][ni][0]), f2bf(acc[mi][ni][1]),
                                   f2bf(acc[mi][ni][2]), f2bf(acc[mi][ni][3]));
          *(ushort4*)(stg + off) = p;
        }
      }
    }
    __syncthreads();
    const int bb2 = rowBase >> 11;
    const int hh0 = (colBase & 511) >> 6;
    const int tile0 = (rowBase & 2047) >> 5;
    unsigned short* gout = (unsigned short*)(isV ? out1 : out0);
    #pragma unroll
    for (int ridx = 0; ridx < 8; ridx++) {
      int hl = ridx >> 2, tl = ridx & 3;
      size_t gb = ((size_t)((bb2 * 8 + hh0 + hl) * 64 + tile0 + tl)) * 2048 + t * 8;
      *(uint4*)(gout + gb) = *(const uint4*)(stg + ridx * 2048 + t * 8);
    }
  }
}

__global__ __launch_bounds__(256) void k_qkv(
    const unsigned short* __restrict__ xn, const unsigned short* __restrict__ WqT,
    unsigned short* __restrict__ Qp,
    const unsigned short* __restrict__ cb, const unsigned short* __restrict__ WkvT,
    unsigned short* __restrict__ Kp, unsigned short* __restrict__ Vp)
{
  __shared__ __align__(16) unsigned short smem[128 * 128];
  int bid = blockIdx.x;
  if (bid < 128) gemm_body<0>(xn, WqT, Qp, nullptr, bid & 3, bid >> 2, smem);
  else { int b2 = bid - 128; gemm_body<1>(cb, WkvT, Kp, Vp, b2 & 7, b2 >> 3, smem); }
}

__global__ __launch_bounds__(256) void k_oproj(
    const unsigned short* __restrict__ ao, const unsigned short* __restrict__ WoT,
    float* __restrict__ proj)
{
  __shared__ __align__(16) unsigned short smem[128 * 128];
  int bid = blockIdx.x;
  gemm_body<2>(ao, WoT, proj, nullptr, bid & 3, bid >> 2, smem);
}

// ---------------- flash attention v4 ----------------
// 1024 blocks, 4 waves; XCD-swizzled decode. Wave w owns kv quarter [w*512, +512).
// Q/K/V all fragment-packed: every load is a coalesced 16B/lane.
// Single K/V buffer + early-issue prefetch (no spill); launch_bounds(256,3).
__global__ __launch_bounds__(256, 3) void k_attn(
    const unsigned short* __restrict__ Qp, const unsigned short* __restrict__ Kp,
    const unsigned short* __restrict__ Vp, const unsigned int* __restrict__ mb,
    unsigned short* __restrict__ O)
{
  __shared__ __align__(16) float mbuf[3][64][34];   // acc(32) + m + l per lane
  const int t = threadIdx.x, lane = t & 63, q5 = lane & 31, hi = lane >> 5;
  const int w = t >> 6;
  const int bid = blockIdx.x;
  const int bh = (bid & 7) * 2 + (bid >> 9);        // XCD-local bh pair
  const int qt = (bid >> 3) & 63;
  const int q0 = qt * 32;
  const int b = bh >> 3, h = bh & 7;
  const float C2f = 0.022542110013890053f;          // SCALE^2 * log2(e)

  bf16x8 qf[4];
  {
    const unsigned short* qp = Qp + (size_t)(bh * 64 + qt) * 2048 + lane * 8;
    #pragma unroll
    for (int kk = 0; kk < 4; kk++) qf[kk] = *(const bf16x8*)(qp + kk * 512);
  }
  const unsigned short* kpb = Kp + (size_t)bh * 131072 + lane * 8;
  const unsigned short* vpb = Vp + (size_t)bh * 131072 + lane * 8;
  const unsigned int* mbp = mb + b * 64;

  float mrun = -3e38f, lrun = 0.f;
  f32x16 acc0, acc1;
  #pragma unroll
  for (int i = 0; i < 16; i++) { acc0[i] = 0.f; acc1[i] = 0.f; }

  bf16x8 kf[4], vf[4];
  auto loadK = [&](int tile) {
    #pragma unroll
    for (int kk = 0; kk < 4; kk++)
      kf[kk] = *(const bf16x8*)(kpb + (size_t)tile * 2048 + kk * 512);
  };
  auto loadV = [&](int tile) {
    #pragma unroll
    for (int i = 0; i < 4; i++)
      vf[i] = *(const bf16x8*)(vpb + (size_t)tile * 2048 + i * 512);
  };

  const int tb = w * 16;
  loadK(tb); loadV(tb);
  for (int it = 0; it < 16; ++it) {
    const int ti = tb + it;

    // ---- QK^T ----
    f32x16 s;
    #pragma unroll
    for (int i = 0; i < 16; i++) s[i] = 0.f;
    #pragma unroll
    for (int kk = 0; kk < 4; kk++) s = MFMA32(kf[kk], qf[kk], s);
    if (it < 15) loadK(ti + 1);      // kf dead: prefetch next K under softmax+PV

    // ---- online softmax ----
    float m0 = fmaxf(fmaxf(s[0], s[1]),  fmaxf(s[2], s[3]));
    float m1 = fmaxf(fmaxf(s[4], s[5]),  fmaxf(s[6], s[7]));
    float m2 = fmaxf(fmaxf(s[8], s[9]),  fmaxf(s[10], s[11]));
    float m3 = fmaxf(fmaxf(s[12], s[13]), fmaxf(s[14], s[15]));
    float tmax = fmaxf(fmaxf(m0, m1), fmaxf(m2, m3));
    tmax = fmaxf(tmax, __shfl_xor(tmax, 32));
    if (!__all(tmax <= mrun + 400.f)) {             // defer-max: rare
      float mnew = fmaxf(mrun, tmax);
      float sf = fexp2((mrun - mnew) * C2f);
      lrun *= sf;
      #pragma unroll
      for (int i = 0; i < 16; i++) { acc0[i] *= sf; acc1[i] *= sf; }
      mrun = mnew;
    }
    unsigned mh = mbp[ti] >> (hi * 4);
    float nb = -mrun * C2f;
    float p[16];
    #pragma unroll
    for (int r = 0; r < 16; r++) {
      float pv = fexp2(fmaf(s[r], C2f, nb));
      p[r] = ((mh >> ((r & 3) + 8 * (r >> 2))) & 1u) ? pv : 0.f;
    }
    float rsa = (p[0] + p[1]) + (p[2] + p[3]);
    float rsb = (p[4] + p[5]) + (p[6] + p[7]);
    float rsc = (p[8] + p[9]) + (p[10] + p[11]);
    float rsd = (p[12] + p[13]) + (p[14] + p[15]);
    float rs = (rsa + rsb) + (rsc + rsd);
    rs += __shfl_xor(rs, 32);
    lrun += rs;

    unsigned wd[8];
    #pragma unroll
    for (int i = 0; i < 8; i++) wd[i] = cvtpk(p[2 * i], p[2 * i + 1]);
    plswap(wd[0], wd[2]); plswap(wd[1], wd[3]);
    plswap(wd[4], wd[6]); plswap(wd[5], wd[7]);
    union { unsigned u[4]; bf16x8 v; } U0, U1;
    U0.u[0] = wd[0]; U0.u[1] = wd[1]; U0.u[2] = wd[2]; U0.u[3] = wd[3];
    U1.u[0] = wd[4]; U1.u[1] = wd[5]; U1.u[2] = wd[6]; U1.u[3] = wd[7];

    // ---- PV ----
    acc0 = MFMA32(vf[0], U0.v, acc0);
    acc0 = MFMA32(vf[1], U1.v, acc0);
    acc1 = MFMA32(vf[2], U0.v, acc1);
    acc1 = MFMA32(vf[3], U1.v, acc1);
    if (it < 15) loadV(ti + 1);      // vf dead: prefetch next V under next QK+softmax
  }

  // ---- 4-way merge ----
  if (w) {
    #pragma unroll
    for (int i = 0; i < 16; i++) { mbuf[w-1][lane][i] = acc0[i]; mbuf[w-1][lane][16 + i] = acc1[i]; }
    mbuf[w-1][lane][32] = mrun; mbuf[w-1][lane][33] = lrun;
  }
  __syncthreads();
  if (!w) {
    float mo[3], lo[3];
    #pragma unroll
    for (int wv = 0; wv < 3; wv++) { mo[wv] = mbuf[wv][lane][32]; lo[wv] = mbuf[wv][lane][33]; }
    float mN = fmaxf(fmaxf(mrun, mo[0]), fmaxf(mo[1], mo[2]));
    float sf0 = fexp2((mrun - mN) * C2f);
    float sfv[3];
    float lsum = lrun * sf0;
    #pragma unroll
    for (int wv = 0; wv < 3; wv++) { sfv[wv] = fexp2((mo[wv] - mN) * C2f); lsum += lo[wv] * sfv[wv]; }
    float linv = 1.f / lsum;
    float a2[32];
    #pragma unroll
    for (int i = 0; i < 16; i++) {
      float v0 = acc0[i] * sf0, v1 = acc1[i] * sf0;
      #pragma unroll
      for (int wv = 0; wv < 3; wv++) {
        v0 += mbuf[wv][lane][i] * sfv[wv];
        v1 += mbuf[wv][lane][16 + i] * sfv[wv];
      }
      a2[i] = v0 * linv;
      a2[16 + i] = v1 * linv;
    }
    // transpose O^T[d][q] -> O[q][d] via LDS (stride 72 shorts, 16B-aligned rows)
    unsigned short* ot = (unsigned short*)&mbuf[0][0][0];
    #pragma unroll
    for (int d2 = 0; d2 < 2; d2++)
      #pragma unroll
      for (int i = 0; i < 8; i++) {
        int d0 = ((2 * i) & 3) + 8 * (i >> 1) + 4 * hi + 32 * d2;
        unsigned wv2 = cvtpk(a2[d2 * 16 + 2 * i], a2[d2 * 16 + 2 * i + 1]);
        *(unsigned*)(ot + q5 * 72 + d0) = wv2;
      }
    #pragma unroll
    for (int it2 = 0; it2 < 4; ++it2) {
      int row = (lane >> 3) + it2 * 8, ch = lane & 7;
      uint4 val = *(const uint4*)(ot + row * 72 + ch * 8);
      *(uint4*)(O + ((size_t)(b * 2048 + q0 + row)) * 512 + h * 64 + ch * 8) = val;
    }
  }
}

// ---------------- host ----------------
extern "C" void kernel_launch(void* const* d_in, const int* in_sizes, int n_in,
                              void* d_out, int out_size, void* d_ws, size_t ws_size,
                              hipStream_t stream) {
  const float* x     = (const float*)d_in[0];
  const float* ctx   = (const float*)d_in[1];
  const int*   mask  = (const int*)d_in[2];
  const float* ln_g  = (const float*)d_in[3];
  const float* ln_b  = (const float*)d_in[4];
  const float* Wq    = (const float*)d_in[5];
  const float* Wkv   = (const float*)d_in[6];
  const float* Wo    = (const float*)d_in[7];
  const float* lno_g = (const float*)d_in[8];
  const float* lno_b = (const float*)d_in[9];
  float* out = (float*)d_out;

  char* ws = (char*)d_ws;
  unsigned short* WqT  = (unsigned short*)(ws + 0);                         // 512 KB
  unsigned short* WkvT = (unsigned short*)(ws + (size_t)1 * (1 << 19));     // 1 MB
  unsigned short* WoT  = (unsigned short*)(ws + (size_t)3 * (1 << 19));     // 512 KB
  unsigned short* xn   = (unsigned short*)(ws + (size_t)2  * (1 << 20));    // 4 MB
  unsigned short* cb   = (unsigned short*)(ws + (size_t)6  * (1 << 20));    // 4 MB
  unsigned short* Qp   = (unsigned short*)(ws + (size_t)10 * (1 << 20));    // 4 MB (fragment-packed)
  unsigned short* Kp   = (unsigned short*)(ws + (size_t)14 * (1 << 20));    // 4 MB (fragment-packed)
  unsigned short* Vp   = (unsigned short*)(ws + (size_t)18 * (1 << 20));    // 4 MB (fragment-packed)
  unsigned short* ao   = (unsigned short*)(ws + (size_t)22 * (1 << 20));    // 4 MB
  float* proj          = (float*)(ws + (size_t)26 * (1 << 20));             // 8 MB
  unsigned int* mbw    = (unsigned int*)(ws + (size_t)26 * (1 << 20));      // 512 B, overlaps proj (dead by then)

  k_prep<<<4112, 256, 0, stream>>>(Wq, Wkv, Wo, x, ln_g, ln_b, ctx, mask,
                                   WqT, WkvT, WoT, xn, cb, mbw);
  k_qkv<<<384, 256, 0, stream>>>(xn, WqT, Qp, cb, WkvT, Kp, Vp);
  k_attn<<<1024, 256, 0, stream>>>(Qp, Kp, Vp, mbw, ao);
  k_oproj<<<128, 256, 0, stream>>>(ao, WoT, proj);
  k_layernorm_f<<<1024, 256, 0, stream>>>(proj, lno_g, lno_b, out);
}

// Round 6
// 98.277 us; speedup vs baseline: 2.0079x; 1.0876x over previous
//
#include <hip/hip_runtime.h>
#include <stdint.h>

typedef float f32x4 __attribute__((ext_vector_type(4)));
typedef float f32x16 __attribute__((ext_vector_type(16)));
typedef __bf16 bf16x8 __attribute__((ext_vector_type(8)));
typedef unsigned int uint2v __attribute__((ext_vector_type(2)));

#define MFMA16(a,b,c) __builtin_amdgcn_mfma_f32_16x16x32_bf16((a),(b),(c),0,0,0)
#define MFMA32(a,b,c) __builtin_amdgcn_mfma_f32_32x32x16_bf16((a),(b),(c),0,0,0)

__device__ __forceinline__ unsigned short f2bf(float f){
  unsigned int u = __float_as_uint(f);
  u += 0x7FFFu + ((u >> 16) & 1u);
  return (unsigned short)(u >> 16);
}

__device__ __forceinline__ unsigned cvtpk(float lo, float hi){
  unsigned r;
  asm volatile("v_cvt_pk_bf16_f32 %0, %1, %2" : "=v"(r) : "v"(lo), "v"(hi));
  return r;
}

__device__ __forceinline__ float fexp2(float x){
#if __has_builtin(__builtin_amdgcn_exp2f)
  return __builtin_amdgcn_exp2f(x);
#else
  return exp2f(x);
#endif
}

__device__ __forceinline__ void plswap(unsigned &a, unsigned &b){
#if __has_builtin(__builtin_amdgcn_permlane32_swap)
  uint2v r = __builtin_amdgcn_permlane32_swap(a, b, false, false);
  a = r[0]; b = r[1];
#else
  unsigned xa = __shfl_xor(a, 32), xb = __shfl_xor(b, 32);
  int hi = (threadIdx.x & 63) >> 5;
  unsigned na = hi ? xb : a;
  unsigned nb = hi ? b : xa;
  a = na; b = nb;
#endif
}

// ---------------- prep router: weight transposes + LN(x) + cast(ctx) + maskbits ----------------
__global__ __launch_bounds__(256) void k_prep(
    const float* __restrict__ Wq, const float* __restrict__ Wkv, const float* __restrict__ Wo,
    const float* __restrict__ x, const float* __restrict__ ln_g, const float* __restrict__ ln_b,
    const float* __restrict__ ctx, const int* __restrict__ mask,
    unsigned short* __restrict__ WqT, unsigned short* __restrict__ WkvT, unsigned short* __restrict__ WoT,
    unsigned short* __restrict__ xn, unsigned short* __restrict__ cb, unsigned int* __restrict__ mb)
{
  __shared__ float tile[32][33];
  const int bid = blockIdx.x, t = threadIdx.x;
  if (bid < 1024) {
    const float* W; unsigned short* WT; int N, bx, by;
    if (bid < 256)      { W = Wq;  WT = WqT;  N = 512;  bx = bid & 15;        by = bid >> 4; }
    else if (bid < 768) { W = Wkv; WT = WkvT; N = 1024; bx = (bid-256) & 31;  by = (bid-256) >> 5; }
    else                { W = Wo;  WT = WoT;  N = 512;  bx = (bid-768) & 15;  by = (bid-768) >> 4; }
    const int tx = t & 31, ty = t >> 5;
    #pragma unroll
    for (int i = 0; i < 4; i++)
      tile[ty + i*8][tx] = W[(size_t)(by*32 + ty + i*8) * N + bx*32 + tx];
    __syncthreads();
    #pragma unroll
    for (int i = 0; i < 4; i++)
      WT[(size_t)(bx*32 + ty + i*8) * 512 + by*32 + tx] = f2bf(tile[tx][ty + i*8]);
  } else if (bid < 2048) {
    int row = (bid - 1024) * 4 + (t >> 6);
    int lane = t & 63;
    const float4* xr = (const float4*)(x + (size_t)row * 512);
    float4 a = xr[lane], c = xr[64 + lane];
    float s = a.x + a.y + a.z + a.w + c.x + c.y + c.z + c.w;
    #pragma unroll
    for (int o = 32; o; o >>= 1) s += __shfl_xor(s, o);
    float mu = s * (1.0f / 512.0f);
    float va = (a.x-mu)*(a.x-mu) + (a.y-mu)*(a.y-mu) + (a.z-mu)*(a.z-mu) + (a.w-mu)*(a.w-mu)
             + (c.x-mu)*(c.x-mu) + (c.y-mu)*(c.y-mu) + (c.z-mu)*(c.z-mu) + (c.w-mu)*(c.w-mu);
    #pragma unroll
    for (int o = 32; o; o >>= 1) va += __shfl_xor(va, o);
    float inv = rsqrtf(va * (1.0f / 512.0f) + 1e-5f);
    const float4* gp = (const float4*)ln_g;
    const float4* bp = (const float4*)ln_b;
    float4 g0 = gp[lane], g1 = gp[64 + lane], b0 = bp[lane], b1 = bp[64 + lane];
    ushort4* op = (ushort4*)(xn + (size_t)row * 512);
    op[lane]      = make_ushort4(f2bf((a.x-mu)*inv*g0.x + b0.x), f2bf((a.y-mu)*inv*g0.y + b0.y),
                                 f2bf((a.z-mu)*inv*g0.z + b0.z), f2bf((a.w-mu)*inv*g0.w + b0.w));
    op[64 + lane] = make_ushort4(f2bf((c.x-mu)*inv*g1.x + b1.x), f2bf((c.y-mu)*inv*g1.y + b1.y),
                                 f2bf((c.z-mu)*inv*g1.z + b1.z), f2bf((c.w-mu)*inv*g1.w + b1.w));
  } else if (bid < 4096) {
    int i = (bid - 2048) * 256 + t;
    float4 v = ((const float4*)ctx)[i];
    ((ushort4*)cb)[i] = make_ushort4(f2bf(v.x), f2bf(v.y), f2bf(v.z), f2bf(v.w));
  } else {
    int g = (bid - 4096) * 4 + (t >> 6);
    int ln = t & 63;
    int v = mask[g * 64 + ln];
    unsigned long long bb = __ballot(v != 0);
    if (ln == 0) { mb[g*2] = (unsigned)bb; mb[g*2+1] = (unsigned)(bb >> 32); }
  }
}

// ---------------- final layernorm (f32 in/out) ----------------
__global__ __launch_bounds__(256) void k_layernorm_f(
    const float* __restrict__ X, const float* __restrict__ G,
    const float* __restrict__ Bt, float* __restrict__ out)
{
  int row = blockIdx.x * 4 + (threadIdx.x >> 6);
  int lane = threadIdx.x & 63;
  const float4* xr = (const float4*)(X + (size_t)row * 512);
  float4 a = xr[lane], c = xr[64 + lane];
  float s = a.x + a.y + a.z + a.w + c.x + c.y + c.z + c.w;
  #pragma unroll
  for (int o = 32; o; o >>= 1) s += __shfl_xor(s, o);
  float mu = s * (1.0f / 512.0f);
  float va = (a.x-mu)*(a.x-mu) + (a.y-mu)*(a.y-mu) + (a.z-mu)*(a.z-mu) + (a.w-mu)*(a.w-mu)
           + (c.x-mu)*(c.x-mu) + (c.y-mu)*(c.y-mu) + (c.z-mu)*(c.z-mu) + (c.w-mu)*(c.w-mu);
  #pragma unroll
  for (int o = 32; o; o >>= 1) va += __shfl_xor(va, o);
  float inv = rsqrtf(va * (1.0f / 512.0f) + 1e-5f);
  const float4* gp = (const float4*)G;
  const float4* bp = (const float4*)Bt;
  float4 g0 = gp[lane], g1 = gp[64 + lane], b0 = bp[lane], b1 = bp[64 + lane];
  float4 y0, y1;
  y0.x = (a.x-mu)*inv*g0.x + b0.x; y0.y = (a.y-mu)*inv*g0.y + b0.y;
  y0.z = (a.z-mu)*inv*g0.z + b0.z; y0.w = (a.w-mu)*inv*g0.w + b0.w;
  y1.x = (c.x-mu)*inv*g1.x + b1.x; y1.y = (c.y-mu)*inv*g1.y + b1.y;
  y1.z = (c.z-mu)*inv*g1.z + b1.z; y1.w = (c.w-mu)*inv*g1.w + b1.w;
  float4* op = (float4*)(out + (size_t)row * 512);
  op[lane] = y0; op[64 + lane] = y1;
}

// ---------------- bf16 MFMA GEMM body: 64x128 tile, BK=64, 4 waves (2x2), dbuf LDS ----------------
// MODE 0: fragment-packed Q out. MODE 1: KV -> packed Kp (out0, col<512) / Vp (out1).
// MODE 2: f32 out stride 512.
// Packed layouts (per bh, region = tile of 32 idx = 2048 shorts):
//  Kp/Qp: region*2048 + (d>>4)*512 + ((i&31) + 32*((d>>3)&1))*8 + (d&7)
//  Vp:    region*2048 + (d>>5)*1024 + ((kv>>4)&1)*512 + ((d&31) + 32*((kv>>3)&1))*8 + (kv&7)
template<int MODE>
__device__ __forceinline__ void gemm_body(
    const unsigned short* __restrict__ A, const unsigned short* __restrict__ BT,
    void* __restrict__ out0, void* __restrict__ out1, int bx, int by,
    unsigned short* smem)
{
  unsigned short* As = smem;              // [2][64*64]  = 16 KB
  unsigned short* Bs = smem + 2*64*64;    // [2][128*64] = 32 KB
  const int t = threadIdx.x;
  const int lane = t & 63, l16 = lane & 15, lhi = lane >> 4;
  const int w = t >> 6, wm = w >> 1, wn = w & 1;
  const int rowBase = by * 64;
  const int colBase = bx * 128;

  f32x4 acc[2][4];
  #pragma unroll
  for (int i = 0; i < 2; i++)
    #pragma unroll
    for (int j = 0; j < 4; j++)
      acc[i][j] = f32x4{0.f, 0.f, 0.f, 0.f};

  uint4 ra[2], rb[4];
  auto gload = [&](int kt) {
    #pragma unroll
    for (int i = 0; i < 2; i++) {
      int c = i * 256 + t, rr = c >> 3, cw = c & 7;
      ra[i] = *(const uint4*)(A + (size_t)(rowBase + rr) * 512 + kt * 64 + cw * 8);
    }
    #pragma unroll
    for (int i = 0; i < 4; i++) {
      int c = i * 256 + t, rr = c >> 3, cw = c & 7;
      rb[i] = *(const uint4*)(BT + (size_t)(colBase + rr) * 512 + kt * 64 + cw * 8);
    }
  };
  auto lstore = [&](int buf) {
    char* Ab = (char*)(As + buf * 4096);
    char* Bb = (char*)(Bs + buf * 8192);
    #pragma unroll
    for (int i = 0; i < 2; i++) {
      int c = i * 256 + t, rr = c >> 3, cw = c & 7, sz = cw ^ (rr & 7);
      *(uint4*)(Ab + rr * 128 + sz * 16) = ra[i];
    }
    #pragma unroll
    for (int i = 0; i < 4; i++) {
      int c = i * 256 + t, rr = c >> 3, cw = c & 7, sz = cw ^ (rr & 7);
      *(uint4*)(Bb + rr * 128 + sz * 16) = rb[i];
    }
  };

  gload(0);
  lstore(0);
  gload(1);
  for (int kt = 0; kt < 8; ++kt) {
    __syncthreads();                       // buf[kt&1] visible; buf[kt&1^1] free to overwrite
    const int buf = kt & 1;
    if (kt < 7) lstore(buf ^ 1);
    if (kt < 6) gload(kt + 2);
    const char* Ab = (const char*)(As + buf * 4096);
    const char* Bb = (const char*)(Bs + buf * 8192);
    #pragma unroll
    for (int ks = 0; ks < 2; ++ks) {
      bf16x8 af[2], bb[4];
      #pragma unroll
      for (int mi = 0; mi < 2; mi++) {
        int rr = wm * 32 + mi * 16 + l16;
        int cc = ks * 4 + lhi;
        af[mi] = *(const bf16x8*)(Ab + rr * 128 + ((cc ^ (rr & 7)) * 16));
      }
      #pragma unroll
      for (int ni = 0; ni < 4; ni++) {
        int rr = wn * 64 + ni * 16 + l16;
        int cc = ks * 4 + lhi;
        bb[ni] = *(const bf16x8*)(Bb + rr * 128 + ((cc ^ (rr & 7)) * 16));
      }
      #pragma unroll
      for (int mi = 0; mi < 2; mi++)
        #pragma unroll
        for (int ni = 0; ni < 4; ni++)
          acc[mi][ni] = MFMA16(af[mi], bb[ni], acc[mi][ni]);
    }
  }
  __syncthreads();                         // done with LDS K-buffers

  if constexpr (MODE == 2) {
    const int r0 = rowBase + wm * 32 + lhi * 4;
    const int c0 = colBase + wn * 64 + l16;
    #pragma unroll
    for (int mi = 0; mi < 2; mi++)
      #pragma unroll
      for (int ni = 0; ni < 4; ni++)
        #pragma unroll
        for (int r = 0; r < 4; r++)
          ((float*)out0)[(size_t)(r0 + mi * 16 + r) * 512 + c0 + ni * 16] = acc[mi][ni][r];
  } else {
    // stage 64x128 packed tile (4 regions x 2048 shorts = 16 KB) in LDS, then coalesced write
    unsigned short* stg = smem;
    const bool isV = (MODE == 1) && (colBase >= 512);
    if (!isV) {
      #pragma unroll
      for (int mi = 0; mi < 2; mi++) {
        int rl = wm * 32 + mi * 16 + lhi * 4;
        int tl = rl >> 5;
        #pragma unroll
        for (int ni = 0; ni < 4; ni++) {
          int cl = wn * 64 + ni * 16 + l16;
          int hl = cl >> 6, d = cl & 63;
          int rbase = (hl * 2 + tl) * 2048 + (d >> 4) * 512 + 256 * ((d >> 3) & 1) + (d & 7);
          #pragma unroll
          for (int r = 0; r < 4; r++)
            stg[rbase + ((rl + r) & 31) * 8] = f2bf(acc[mi][ni][r]);
        }
      }
    } else {
      #pragma unroll
      for (int mi = 0; mi < 2; mi++) {
        int rl = wm * 32 + mi * 16 + lhi * 4;
        int tl = rl >> 5, kvr = rl & 31;
        #pragma unroll
        for (int ni = 0; ni < 4; ni++) {
          int cl = wn * 64 + ni * 16 + l16;
          int hl = cl >> 6, d = cl & 63;
          int off = (hl * 2 + tl) * 2048 + (d >> 5) * 1024 + ((kvr >> 4) & 1) * 512
                  + ((d & 31) + 32 * ((kvr >> 3) & 1)) * 8 + (kvr & 7);
          ushort4 p = make_ushort4(f2bf(acc[mi][ni][0]), f2bf(acc[mi][ni][1]),
                                   f2bf(acc[mi][ni][2]), f2bf(acc[mi][ni][3]));
          *(ushort4*)(stg + off) = p;
        }
      }
    }
    __syncthreads();
    const int bb2 = rowBase >> 11;
    const int hh0 = (colBase & 511) >> 6;
    const int tile0 = (rowBase & 2047) >> 5;
    unsigned short* gout = (unsigned short*)(isV ? out1 : out0);
    #pragma unroll
    for (int ridx = 0; ridx < 4; ridx++) {
      int hl = ridx >> 1, tl = ridx & 1;
      size_t gb = ((size_t)((bb2 * 8 + hh0 + hl) * 64 + tile0 + tl)) * 2048 + t * 8;
      *(uint4*)(gout + gb) = *(const uint4*)(stg + ridx * 2048 + t * 8);
    }
  }
}

// 768 blocks: xcd = bid&7 owns M-stripe of 512 rows (8 mtiles x 12 coltiles).
__global__ __launch_bounds__(256) void k_qkv(
    const unsigned short* __restrict__ xn, const unsigned short* __restrict__ WqT,
    unsigned short* __restrict__ Qp,
    const unsigned short* __restrict__ cb, const unsigned short* __restrict__ WkvT,
    unsigned short* __restrict__ Kp, unsigned short* __restrict__ Vp)
{
  __shared__ __align__(16) unsigned short smem[2*64*64 + 2*128*64];
  const int bid = blockIdx.x;
  const int xcd = bid & 7, loc = bid >> 3;
  const int mloc = loc / 12, ct = loc % 12;
  const int mtile = xcd * 8 + mloc;
  if (ct < 4) gemm_body<0>(xn, WqT, Qp, nullptr, ct, mtile, smem);
  else        gemm_body<1>(cb, WkvT, Kp, Vp, ct - 4, mtile, smem);
}

// 256 blocks: xcd stripe, 8 mtiles x 4 coltiles per xcd.
__global__ __launch_bounds__(256) void k_oproj(
    const unsigned short* __restrict__ ao, const unsigned short* __restrict__ WoT,
    float* __restrict__ proj)
{
  __shared__ __align__(16) unsigned short smem[2*64*64 + 2*128*64];
  const int bid = blockIdx.x;
  const int xcd = bid & 7, loc = bid >> 3;
  const int mloc = loc >> 2, ct = loc & 3;
  const int mtile = xcd * 8 + mloc;
  gemm_body<2>(ao, WoT, proj, nullptr, ct, mtile, smem);
}

// ---------------- flash attention v4 ----------------
// 1024 blocks, 4 waves; XCD-swizzled decode. Wave w owns kv quarter [w*512, +512).
// Q/K/V all fragment-packed: every load is a coalesced 16B/lane.
// Single K/V buffer + early-issue prefetch (no spill); launch_bounds(256,3).
__global__ __launch_bounds__(256, 3) void k_attn(
    const unsigned short* __restrict__ Qp, const unsigned short* __restrict__ Kp,
    const unsigned short* __restrict__ Vp, const unsigned int* __restrict__ mb,
    unsigned short* __restrict__ O)
{
  __shared__ __align__(16) float mbuf[3][64][34];   // acc(32) + m + l per lane
  const int t = threadIdx.x, lane = t & 63, q5 = lane & 31, hi = lane >> 5;
  const int w = t >> 6;
  const int bid = blockIdx.x;
  const int bh = (bid & 7) * 2 + (bid >> 9);        // XCD-local bh pair
  const int qt = (bid >> 3) & 63;
  const int q0 = qt * 32;
  const int b = bh >> 3, h = bh & 7;
  const float C2f = 0.022542110013890053f;          // SCALE^2 * log2(e)

  bf16x8 qf[4];
  {
    const unsigned short* qp = Qp + (size_t)(bh * 64 + qt) * 2048 + lane * 8;
    #pragma unroll
    for (int kk = 0; kk < 4; kk++) qf[kk] = *(const bf16x8*)(qp + kk * 512);
  }
  const unsigned short* kpb = Kp + (size_t)bh * 131072 + lane * 8;
  const unsigned short* vpb = Vp + (size_t)bh * 131072 + lane * 8;
  const unsigned int* mbp = mb + b * 64;

  float mrun = -3e38f, lrun = 0.f;
  f32x16 acc0, acc1;
  #pragma unroll
  for (int i = 0; i < 16; i++) { acc0[i] = 0.f; acc1[i] = 0.f; }

  bf16x8 kf[4], vf[4];
  auto loadK = [&](int tile) {
    #pragma unroll
    for (int kk = 0; kk < 4; kk++)
      kf[kk] = *(const bf16x8*)(kpb + (size_t)tile * 2048 + kk * 512);
  };
  auto loadV = [&](int tile) {
    #pragma unroll
    for (int i = 0; i < 4; i++)
      vf[i] = *(const bf16x8*)(vpb + (size_t)tile * 2048 + i * 512);
  };

  const int tb = w * 16;
  loadK(tb); loadV(tb);
  for (int it = 0; it < 16; ++it) {
    const int ti = tb + it;

    // ---- QK^T ----
    f32x16 s;
    #pragma unroll
    for (int i = 0; i < 16; i++) s[i] = 0.f;
    #pragma unroll
    for (int kk = 0; kk < 4; kk++) s = MFMA32(kf[kk], qf[kk], s);
    if (it < 15) loadK(ti + 1);      // kf dead: prefetch next K under softmax+PV

    // ---- online softmax ----
    float m0 = fmaxf(fmaxf(s[0], s[1]),  fmaxf(s[2], s[3]));
    float m1 = fmaxf(fmaxf(s[4], s[5]),  fmaxf(s[6], s[7]));
    float m2 = fmaxf(fmaxf(s[8], s[9]),  fmaxf(s[10], s[11]));
    float m3 = fmaxf(fmaxf(s[12], s[13]), fmaxf(s[14], s[15]));
    float tmax = fmaxf(fmaxf(m0, m1), fmaxf(m2, m3));
    tmax = fmaxf(tmax, __shfl_xor(tmax, 32));
    if (!__all(tmax <= mrun + 400.f)) {             // defer-max: rare
      float mnew = fmaxf(mrun, tmax);
      float sf = fexp2((mrun - mnew) * C2f);
      lrun *= sf;
      #pragma unroll
      for (int i = 0; i < 16; i++) { acc0[i] *= sf; acc1[i] *= sf; }
      mrun = mnew;
    }
    unsigned mh = mbp[ti] >> (hi * 4);
    float nb = -mrun * C2f;
    float p[16];
    #pragma unroll
    for (int r = 0; r < 16; r++) {
      float pv = fexp2(fmaf(s[r], C2f, nb));
      p[r] = ((mh >> ((r & 3) + 8 * (r >> 2))) & 1u) ? pv : 0.f;
    }
    float rsa = (p[0] + p[1]) + (p[2] + p[3]);
    float rsb = (p[4] + p[5]) + (p[6] + p[7]);
    float rsc = (p[8] + p[9]) + (p[10] + p[11]);
    float rsd = (p[12] + p[13]) + (p[14] + p[15]);
    float rs = (rsa + rsb) + (rsc + rsd);
    rs += __shfl_xor(rs, 32);
    lrun += rs;

    unsigned wd[8];
    #pragma unroll
    for (int i = 0; i < 8; i++) wd[i] = cvtpk(p[2 * i], p[2 * i + 1]);
    plswap(wd[0], wd[2]); plswap(wd[1], wd[3]);
    plswap(wd[4], wd[6]); plswap(wd[5], wd[7]);
    union { unsigned u[4]; bf16x8 v; } U0, U1;
    U0.u[0] = wd[0]; U0.u[1] = wd[1]; U0.u[2] = wd[2]; U0.u[3] = wd[3];
    U1.u[0] = wd[4]; U1.u[1] = wd[5]; U1.u[2] = wd[6]; U1.u[3] = wd[7];

    // ---- PV ----
    acc0 = MFMA32(vf[0], U0.v, acc0);
    acc0 = MFMA32(vf[1], U1.v, acc0);
    acc1 = MFMA32(vf[2], U0.v, acc1);
    acc1 = MFMA32(vf[3], U1.v, acc1);
    if (it < 15) loadV(ti + 1);      // vf dead: prefetch next V under next QK+softmax
  }

  // ---- 4-way merge ----
  if (w) {
    #pragma unroll
    for (int i = 0; i < 16; i++) { mbuf[w-1][lane][i] = acc0[i]; mbuf[w-1][lane][16 + i] = acc1[i]; }
    mbuf[w-1][lane][32] = mrun; mbuf[w-1][lane][33] = lrun;
  }
  __syncthreads();
  if (!w) {
    float mo[3], lo[3];
    #pragma unroll
    for (int wv = 0; wv < 3; wv++) { mo[wv] = mbuf[wv][lane][32]; lo[wv] = mbuf[wv][lane][33]; }
    float mN = fmaxf(fmaxf(mrun, mo[0]), fmaxf(mo[1], mo[2]));
    float sf0 = fexp2((mrun - mN) * C2f);
    float sfv[3];
    float lsum = lrun * sf0;
    #pragma unroll
    for (int wv = 0; wv < 3; wv++) { sfv[wv] = fexp2((mo[wv] - mN) * C2f); lsum += lo[wv] * sfv[wv]; }
    float linv = 1.f / lsum;
    float a2[32];
    #pragma unroll
    for (int i = 0; i < 16; i++) {
      float v0 = acc0[i] * sf0, v1 = acc1[i] * sf0;
      #pragma unroll
      for (int wv = 0; wv < 3; wv++) {
        v0 += mbuf[wv][lane][i] * sfv[wv];
        v1 += mbuf[wv][lane][16 + i] * sfv[wv];
      }
      a2[i] = v0 * linv;
      a2[16 + i] = v1 * linv;
    }
    // transpose O^T[d][q] -> O[q][d] via LDS (stride 72 shorts, 16B-aligned rows)
    unsigned short* ot = (unsigned short*)&mbuf[0][0][0];
    #pragma unroll
    for (int d2 = 0; d2 < 2; d2++)
      #pragma unroll
      for (int i = 0; i < 8; i++) {
        int d0 = ((2 * i) & 3) + 8 * (i >> 1) + 4 * hi + 32 * d2;
        unsigned wv2 = cvtpk(a2[d2 * 16 + 2 * i], a2[d2 * 16 + 2 * i + 1]);
        *(unsigned*)(ot + q5 * 72 + d0) = wv2;
      }
    #pragma unroll
    for (int it2 = 0; it2 < 4; ++it2) {
      int row = (lane >> 3) + it2 * 8, ch = lane & 7;
      uint4 val = *(const uint4*)(ot + row * 72 + ch * 8);
      *(uint4*)(O + ((size_t)(b * 2048 + q0 + row)) * 512 + h * 64 + ch * 8) = val;
    }
  }
}

// ---------------- host ----------------
extern "C" void kernel_launch(void* const* d_in, const int* in_sizes, int n_in,
                              void* d_out, int out_size, void* d_ws, size_t ws_size,
                              hipStream_t stream) {
  const float* x     = (const float*)d_in[0];
  const float* ctx   = (const float*)d_in[1];
  const int*   mask  = (const int*)d_in[2];
  const float* ln_g  = (const float*)d_in[3];
  const float* ln_b  = (const float*)d_in[4];
  const float* Wq    = (const float*)d_in[5];
  const float* Wkv   = (const float*)d_in[6];
  const float* Wo    = (const float*)d_in[7];
  const float* lno_g = (const float*)d_in[8];
  const float* lno_b = (const float*)d_in[9];
  float* out = (float*)d_out;

  char* ws = (char*)d_ws;
  unsigned short* WqT  = (unsigned short*)(ws + 0);                         // 512 KB
  unsigned short* WkvT = (unsigned short*)(ws + (size_t)1 * (1 << 19));     // 1 MB
  unsigned short* WoT  = (unsigned short*)(ws + (size_t)3 * (1 << 19));     // 512 KB
  unsigned short* xn   = (unsigned short*)(ws + (size_t)2  * (1 << 20));    // 4 MB
  unsigned short* cb   = (unsigned short*)(ws + (size_t)6  * (1 << 20));    // 4 MB
  unsigned short* Qp   = (unsigned short*)(ws + (size_t)10 * (1 << 20));    // 4 MB (fragment-packed)
  unsigned short* Kp   = (unsigned short*)(ws + (size_t)14 * (1 << 20));    // 4 MB (fragment-packed)
  unsigned short* Vp   = (unsigned short*)(ws + (size_t)18 * (1 << 20));    // 4 MB (fragment-packed)
  unsigned short* ao   = (unsigned short*)(ws + (size_t)22 * (1 << 20));    // 4 MB
  float* proj          = (float*)(ws + (size_t)26 * (1 << 20));             // 8 MB
  unsigned int* mbw    = (unsigned int*)(ws + (size_t)26 * (1 << 20));      // 512 B, overlaps proj (dead by then)

  k_prep<<<4112, 256, 0, stream>>>(Wq, Wkv, Wo, x, ln_g, ln_b, ctx, mask,
                                   WqT, WkvT, WoT, xn, cb, mbw);
  k_qkv<<<768, 256, 0, stream>>>(xn, WqT, Qp, cb, WkvT, Kp, Vp);
  k_attn<<<1024, 256, 0, stream>>>(Qp, Kp, Vp, mbw, ao);
  k_oproj<<<256, 256, 0, stream>>>(ao, WoT, proj);
  k_layernorm_f<<<1024, 256, 0, stream>>>(proj, lno_g, lno_b, out);
}

// Round 7
// 63.127 us; speedup vs baseline: 3.1259x; 1.5568x over previous
//
#include <hip/hip_runtime.h>
#include <stdint.h>

typedef float f32x4 __attribute__((ext_vector_type(4)));
typedef float f32x16 __attribute__((ext_vector_type(16)));
typedef __bf16 bf16x8 __attribute__((ext_vector_type(8)));
typedef unsigned int uint2v __attribute__((ext_vector_type(2)));

#define MFMA16(a,b,c) __builtin_amdgcn_mfma_f32_16x16x32_bf16((a),(b),(c),0,0,0)
#define MFMA32(a,b,c) __builtin_amdgcn_mfma_f32_32x32x16_bf16((a),(b),(c),0,0,0)

__device__ __forceinline__ unsigned short f2bf(float f){
  unsigned int u = __float_as_uint(f);
  u += 0x7FFFu + ((u >> 16) & 1u);
  return (unsigned short)(u >> 16);
}

__device__ __forceinline__ unsigned cvtpk(float lo, float hi){
  unsigned r;
  asm volatile("v_cvt_pk_bf16_f32 %0, %1, %2" : "=v"(r) : "v"(lo), "v"(hi));
  return r;
}

__device__ __forceinline__ float fexp2(float x){
#if __has_builtin(__builtin_amdgcn_exp2f)
  return __builtin_amdgcn_exp2f(x);
#else
  return exp2f(x);
#endif
}

__device__ __forceinline__ void plswap(unsigned &a, unsigned &b){
#if __has_builtin(__builtin_amdgcn_permlane32_swap)
  uint2v r = __builtin_amdgcn_permlane32_swap(a, b, false, false);
  a = r[0]; b = r[1];
#else
  unsigned xa = __shfl_xor(a, 32), xb = __shfl_xor(b, 32);
  int hi = (threadIdx.x & 63) >> 5;
  unsigned na = hi ? xb : a;
  unsigned nb = hi ? b : xa;
  a = na; b = nb;
#endif
}

// async global -> LDS, 16B per lane; LDS dest is wave-uniform base + lane*16
__device__ __forceinline__ void stage16(const unsigned short* g, unsigned short* l){
  __builtin_amdgcn_global_load_lds(
      (const __attribute__((address_space(1))) void*)g,
      (__attribute__((address_space(3))) void*)l, 16, 0, 0);
}

// ---------------- prep router: weight transposes + LN(x) + cast(ctx) + maskbits ----------------
__global__ __launch_bounds__(256) void k_prep(
    const float* __restrict__ Wq, const float* __restrict__ Wkv, const float* __restrict__ Wo,
    const float* __restrict__ x, const float* __restrict__ ln_g, const float* __restrict__ ln_b,
    const float* __restrict__ ctx, const int* __restrict__ mask,
    unsigned short* __restrict__ WqT, unsigned short* __restrict__ WkvT, unsigned short* __restrict__ WoT,
    unsigned short* __restrict__ xn, unsigned short* __restrict__ cb, unsigned int* __restrict__ mb)
{
  __shared__ float tile[32][33];
  const int bid = blockIdx.x, t = threadIdx.x;
  if (bid < 1024) {
    const float* W; unsigned short* WT; int N, bx, by;
    if (bid < 256)      { W = Wq;  WT = WqT;  N = 512;  bx = bid & 15;        by = bid >> 4; }
    else if (bid < 768) { W = Wkv; WT = WkvT; N = 1024; bx = (bid-256) & 31;  by = (bid-256) >> 5; }
    else                { W = Wo;  WT = WoT;  N = 512;  bx = (bid-768) & 15;  by = (bid-768) >> 4; }
    const int tx = t & 31, ty = t >> 5;
    #pragma unroll
    for (int i = 0; i < 4; i++)
      tile[ty + i*8][tx] = W[(size_t)(by*32 + ty + i*8) * N + bx*32 + tx];
    __syncthreads();
    #pragma unroll
    for (int i = 0; i < 4; i++)
      WT[(size_t)(bx*32 + ty + i*8) * 512 + by*32 + tx] = f2bf(tile[tx][ty + i*8]);
  } else if (bid < 2048) {
    int row = (bid - 1024) * 4 + (t >> 6);
    int lane = t & 63;
    const float4* xr = (const float4*)(x + (size_t)row * 512);
    float4 a = xr[lane], c = xr[64 + lane];
    float s = a.x + a.y + a.z + a.w + c.x + c.y + c.z + c.w;
    #pragma unroll
    for (int o = 32; o; o >>= 1) s += __shfl_xor(s, o);
    float mu = s * (1.0f / 512.0f);
    float va = (a.x-mu)*(a.x-mu) + (a.y-mu)*(a.y-mu) + (a.z-mu)*(a.z-mu) + (a.w-mu)*(a.w-mu)
             + (c.x-mu)*(c.x-mu) + (c.y-mu)*(c.y-mu) + (c.z-mu)*(c.z-mu) + (c.w-mu)*(c.w-mu);
    #pragma unroll
    for (int o = 32; o; o >>= 1) va += __shfl_xor(va, o);
    float inv = rsqrtf(va * (1.0f / 512.0f) + 1e-5f);
    const float4* gp = (const float4*)ln_g;
    const float4* bp = (const float4*)ln_b;
    float4 g0 = gp[lane], g1 = gp[64 + lane], b0 = bp[lane], b1 = bp[64 + lane];
    ushort4* op = (ushort4*)(xn + (size_t)row * 512);
    op[lane]      = make_ushort4(f2bf((a.x-mu)*inv*g0.x + b0.x), f2bf((a.y-mu)*inv*g0.y + b0.y),
                                 f2bf((a.z-mu)*inv*g0.z + b0.z), f2bf((a.w-mu)*inv*g0.w + b0.w));
    op[64 + lane] = make_ushort4(f2bf((c.x-mu)*inv*g1.x + b1.x), f2bf((c.y-mu)*inv*g1.y + b1.y),
                                 f2bf((c.z-mu)*inv*g1.z + b1.z), f2bf((c.w-mu)*inv*g1.w + b1.w));
  } else if (bid < 4096) {
    int i = (bid - 2048) * 256 + t;
    float4 v = ((const float4*)ctx)[i];
    ((ushort4*)cb)[i] = make_ushort4(f2bf(v.x), f2bf(v.y), f2bf(v.z), f2bf(v.w));
  } else {
    int g = (bid - 4096) * 4 + (t >> 6);
    int ln = t & 63;
    int v = mask[g * 64 + ln];
    unsigned long long bb = __ballot(v != 0);
    if (ln == 0) { mb[g*2] = (unsigned)bb; mb[g*2+1] = (unsigned)(bb >> 32); }
  }
}

// ---------------- final layernorm (f32 in/out) ----------------
__global__ __launch_bounds__(256) void k_layernorm_f(
    const float* __restrict__ X, const float* __restrict__ G,
    const float* __restrict__ Bt, float* __restrict__ out)
{
  int row = blockIdx.x * 4 + (threadIdx.x >> 6);
  int lane = threadIdx.x & 63;
  const float4* xr = (const float4*)(X + (size_t)row * 512);
  float4 a = xr[lane], c = xr[64 + lane];
  float s = a.x + a.y + a.z + a.w + c.x + c.y + c.z + c.w;
  #pragma unroll
  for (int o = 32; o; o >>= 1) s += __shfl_xor(s, o);
  float mu = s * (1.0f / 512.0f);
  float va = (a.x-mu)*(a.x-mu) + (a.y-mu)*(a.y-mu) + (a.z-mu)*(a.z-mu) + (a.w-mu)*(a.w-mu)
           + (c.x-mu)*(c.x-mu) + (c.y-mu)*(c.y-mu) + (c.z-mu)*(c.z-mu) + (c.w-mu)*(c.w-mu);
  #pragma unroll
  for (int o = 32; o; o >>= 1) va += __shfl_xor(va, o);
  float inv = rsqrtf(va * (1.0f / 512.0f) + 1e-5f);
  const float4* gp = (const float4*)G;
  const float4* bp = (const float4*)Bt;
  float4 g0 = gp[lane], g1 = gp[64 + lane], b0 = bp[lane], b1 = bp[64 + lane];
  float4 y0, y1;
  y0.x = (a.x-mu)*inv*g0.x + b0.x; y0.y = (a.y-mu)*inv*g0.y + b0.y;
  y0.z = (a.z-mu)*inv*g0.z + b0.z; y0.w = (a.w-mu)*inv*g0.w + b0.w;
  y1.x = (c.x-mu)*inv*g1.x + b1.x; y1.y = (c.y-mu)*inv*g1.y + b1.y;
  y1.z = (c.z-mu)*inv*g1.z + b1.z; y1.w = (c.w-mu)*inv*g1.w + b1.w;
  float4* op = (float4*)(out + (size_t)row * 512);
  op[lane] = y0; op[64 + lane] = y1;
}

// ---------------- bf16 MFMA GEMM body: 64x128 tile, BK=64, 4 waves (2x2) ----------------
// Staging via global_load_lds (async DMA, no staging VGPRs), double-buffered LDS,
// one __syncthreads per K-step. Swizzle applied on the GLOBAL source address;
// LDS dest linear per wave (wave-uniform base + lane*16B).
// MODE 0: fragment-packed Q out. MODE 1: KV -> packed Kp (col<512) / Vp. MODE 2: f32 out.
template<int MODE>
__device__ __forceinline__ void gemm_body(
    const unsigned short* __restrict__ A, const unsigned short* __restrict__ BT,
    void* __restrict__ out0, void* __restrict__ out1, int bx, int by,
    unsigned short* smem)
{
  unsigned short* As = smem;              // [2][64*64]  = 16 KB
  unsigned short* Bs = smem + 2*64*64;    // [2][128*64] = 32 KB
  const int t = threadIdx.x;
  const int lane = t & 63, l16 = lane & 15, lhi = lane >> 4;
  const int w = t >> 6, wm = w >> 1, wn = w & 1;
  const int rowBase = by * 64;
  const int colBase = bx * 128;
  const int srr = lane >> 3, scw = lane & 7;

  f32x4 acc[2][4];
  #pragma unroll
  for (int i = 0; i < 2; i++)
    #pragma unroll
    for (int j = 0; j < 4; j++)
      acc[i][j] = f32x4{0.f, 0.f, 0.f, 0.f};

  auto STAGE = [&](int buf, int kt) {
    unsigned short* Ab = As + buf * 4096;
    unsigned short* Bb = Bs + buf * 8192;
    #pragma unroll
    for (int i = 0; i < 2; i++) {
      int rr = i * 32 + w * 8 + srr;
      stage16(A + (size_t)(rowBase + rr) * 512 + kt * 64 + ((scw ^ (rr & 7)) * 8),
              Ab + (i * 32 + w * 8) * 64);
    }
    #pragma unroll
    for (int i = 0; i < 4; i++) {
      int rr = i * 32 + w * 8 + srr;
      stage16(BT + (size_t)(colBase + rr) * 512 + kt * 64 + ((scw ^ (rr & 7)) * 8),
              Bb + (i * 32 + w * 8) * 64);
    }
  };

  STAGE(0, 0);
  __syncthreads();                         // vmcnt(0) drain + barrier: buf0 ready
  for (int kt = 0; kt < 8; ++kt) {
    const int buf = kt & 1;
    if (kt < 7) STAGE(buf ^ 1, kt + 1);    // async fill of other buffer under compute
    const char* Ab = (const char*)(As + buf * 4096);
    const char* Bb = (const char*)(Bs + buf * 8192);
    #pragma unroll
    for (int ks = 0; ks < 2; ++ks) {
      bf16x8 af[2], bb[4];
      #pragma unroll
      for (int mi = 0; mi < 2; mi++) {
        int rr = wm * 32 + mi * 16 + l16;
        int cc = ks * 4 + lhi;
        af[mi] = *(const bf16x8*)(Ab + rr * 128 + ((cc ^ (rr & 7)) * 16));
      }
      #pragma unroll
      for (int ni = 0; ni < 4; ni++) {
        int rr = wn * 64 + ni * 16 + l16;
        int cc = ks * 4 + lhi;
        bb[ni] = *(const bf16x8*)(Bb + rr * 128 + ((cc ^ (rr & 7)) * 16));
      }
      #pragma unroll
      for (int mi = 0; mi < 2; mi++)
        #pragma unroll
        for (int ni = 0; ni < 4; ni++)
          acc[mi][ni] = MFMA16(af[mi], bb[ni], acc[mi][ni]);
    }
    __syncthreads();                       // drains staged loads; buf^1 ready next iter
  }

  if constexpr (MODE == 2) {
    const int r0 = rowBase + wm * 32 + lhi * 4;
    const int c0 = colBase + wn * 64 + l16;
    #pragma unroll
    for (int mi = 0; mi < 2; mi++)
      #pragma unroll
      for (int ni = 0; ni < 4; ni++)
        #pragma unroll
        for (int r = 0; r < 4; r++)
          ((float*)out0)[(size_t)(r0 + mi * 16 + r) * 512 + c0 + ni * 16] = acc[mi][ni][r];
  } else {
    // stage 64x128 packed tile (4 regions x 2048 shorts = 16 KB) in LDS, then coalesced write
    unsigned short* stg = smem;
    const bool isV = (MODE == 1) && (colBase >= 512);
    if (!isV) {
      #pragma unroll
      for (int mi = 0; mi < 2; mi++) {
        int rl = wm * 32 + mi * 16 + lhi * 4;
        int tl = rl >> 5;
        #pragma unroll
        for (int ni = 0; ni < 4; ni++) {
          int cl = wn * 64 + ni * 16 + l16;
          int hl = cl >> 6, d = cl & 63;
          int rbase = (hl * 2 + tl) * 2048 + (d >> 4) * 512 + 256 * ((d >> 3) & 1) + (d & 7);
          #pragma unroll
          for (int r = 0; r < 4; r++)
            stg[rbase + ((rl + r) & 31) * 8] = f2bf(acc[mi][ni][r]);
        }
      }
    } else {
      #pragma unroll
      for (int mi = 0; mi < 2; mi++) {
        int rl = wm * 32 + mi * 16 + lhi * 4;
        int tl = rl >> 5, kvr = rl & 31;
        #pragma unroll
        for (int ni = 0; ni < 4; ni++) {
          int cl = wn * 64 + ni * 16 + l16;
          int hl = cl >> 6, d = cl & 63;
          int off = (hl * 2 + tl) * 2048 + (d >> 5) * 1024 + ((kvr >> 4) & 1) * 512
                  + ((d & 31) + 32 * ((kvr >> 3) & 1)) * 8 + (kvr & 7);
          ushort4 p = make_ushort4(f2bf(acc[mi][ni][0]), f2bf(acc[mi][ni][1]),
                                   f2bf(acc[mi][ni][2]), f2bf(acc[mi][ni][3]));
          *(ushort4*)(stg + off) = p;
        }
      }
    }
    __syncthreads();
    const int bb2 = rowBase >> 11;
    const int hh0 = (colBase & 511) >> 6;
    const int tile0 = (rowBase & 2047) >> 5;
    unsigned short* gout = (unsigned short*)(isV ? out1 : out0);
    #pragma unroll
    for (int ridx = 0; ridx < 4; ridx++) {
      int hl = ridx >> 1, tl = ridx & 1;
      size_t gb = ((size_t)((bb2 * 8 + hh0 + hl) * 64 + tile0 + tl)) * 2048 + t * 8;
      *(uint4*)(gout + gb) = *(const uint4*)(stg + ridx * 2048 + t * 8);
    }
  }
}

// 768 blocks: xcd = bid&7 owns M-stripe of 512 rows (8 mtiles x 12 coltiles).
__global__ __launch_bounds__(256, 2) void k_qkv(
    const unsigned short* __restrict__ xn, const unsigned short* __restrict__ WqT,
    unsigned short* __restrict__ Qp,
    const unsigned short* __restrict__ cb, const unsigned short* __restrict__ WkvT,
    unsigned short* __restrict__ Kp, unsigned short* __restrict__ Vp)
{
  __shared__ __align__(16) unsigned short smem[2*64*64 + 2*128*64];
  const int bid = blockIdx.x;
  const int xcd = bid & 7, loc = bid >> 3;
  const int mloc = loc / 12, ct = loc % 12;
  const int mtile = xcd * 8 + mloc;
  if (ct < 4) gemm_body<0>(xn, WqT, Qp, nullptr, ct, mtile, smem);
  else        gemm_body<1>(cb, WkvT, Kp, Vp, ct - 4, mtile, smem);
}

// 256 blocks: xcd stripe, 8 mtiles x 4 coltiles per xcd.
__global__ __launch_bounds__(256, 2) void k_oproj(
    const unsigned short* __restrict__ ao, const unsigned short* __restrict__ WoT,
    float* __restrict__ proj)
{
  __shared__ __align__(16) unsigned short smem[2*64*64 + 2*128*64];
  const int bid = blockIdx.x;
  const int xcd = bid & 7, loc = bid >> 3;
  const int mloc = loc >> 2, ct = loc & 3;
  const int mtile = xcd * 8 + mloc;
  gemm_body<2>(ao, WoT, proj, nullptr, ct, mtile, smem);
}

// ---------------- flash attention v4 ----------------
// 1024 blocks, 4 waves; XCD-swizzled decode. Wave w owns kv quarter [w*512, +512).
// Q/K/V all fragment-packed: every load is a coalesced 16B/lane.
// Single K/V buffer + early-issue prefetch (no spill); launch_bounds(256,3).
__global__ __launch_bounds__(256, 3) void k_attn(
    const unsigned short* __restrict__ Qp, const unsigned short* __restrict__ Kp,
    const unsigned short* __restrict__ Vp, const unsigned int* __restrict__ mb,
    unsigned short* __restrict__ O)
{
  __shared__ __align__(16) float mbuf[3][64][34];   // acc(32) + m + l per lane
  const int t = threadIdx.x, lane = t & 63, q5 = lane & 31, hi = lane >> 5;
  const int w = t >> 6;
  const int bid = blockIdx.x;
  const int bh = (bid & 7) * 2 + (bid >> 9);        // XCD-local bh pair
  const int qt = (bid >> 3) & 63;
  const int q0 = qt * 32;
  const int b = bh >> 3, h = bh & 7;
  const float C2f = 0.022542110013890053f;          // SCALE^2 * log2(e)

  bf16x8 qf[4];
  {
    const unsigned short* qp = Qp + (size_t)(bh * 64 + qt) * 2048 + lane * 8;
    #pragma unroll
    for (int kk = 0; kk < 4; kk++) qf[kk] = *(const bf16x8*)(qp + kk * 512);
  }
  const unsigned short* kpb = Kp + (size_t)bh * 131072 + lane * 8;
  const unsigned short* vpb = Vp + (size_t)bh * 131072 + lane * 8;
  const unsigned int* mbp = mb + b * 64;

  float mrun = -3e38f, lrun = 0.f;
  f32x16 acc0, acc1;
  #pragma unroll
  for (int i = 0; i < 16; i++) { acc0[i] = 0.f; acc1[i] = 0.f; }

  bf16x8 kf[4], vf[4];
  auto loadK = [&](int tile) {
    #pragma unroll
    for (int kk = 0; kk < 4; kk++)
      kf[kk] = *(const bf16x8*)(kpb + (size_t)tile * 2048 + kk * 512);
  };
  auto loadV = [&](int tile) {
    #pragma unroll
    for (int i = 0; i < 4; i++)
      vf[i] = *(const bf16x8*)(vpb + (size_t)tile * 2048 + i * 512);
  };

  const int tb = w * 16;
  loadK(tb); loadV(tb);
  for (int it = 0; it < 16; ++it) {
    const int ti = tb + it;

    // ---- QK^T ----
    f32x16 s;
    #pragma unroll
    for (int i = 0; i < 16; i++) s[i] = 0.f;
    #pragma unroll
    for (int kk = 0; kk < 4; kk++) s = MFMA32(kf[kk], qf[kk], s);
    if (it < 15) loadK(ti + 1);      // kf dead: prefetch next K under softmax+PV

    // ---- online softmax ----
    float m0 = fmaxf(fmaxf(s[0], s[1]),  fmaxf(s[2], s[3]));
    float m1 = fmaxf(fmaxf(s[4], s[5]),  fmaxf(s[6], s[7]));
    float m2 = fmaxf(fmaxf(s[8], s[9]),  fmaxf(s[10], s[11]));
    float m3 = fmaxf(fmaxf(s[12], s[13]), fmaxf(s[14], s[15]));
    float tmax = fmaxf(fmaxf(m0, m1), fmaxf(m2, m3));
    tmax = fmaxf(tmax, __shfl_xor(tmax, 32));
    if (!__all(tmax <= mrun + 400.f)) {             // defer-max: rare
      float mnew = fmaxf(mrun, tmax);
      float sf = fexp2((mrun - mnew) * C2f);
      lrun *= sf;
      #pragma unroll
      for (int i = 0; i < 16; i++) { acc0[i] *= sf; acc1[i] *= sf; }
      mrun = mnew;
    }
    unsigned mh = mbp[ti] >> (hi * 4);
    float nb = -mrun * C2f;
    float p[16];
    #pragma unroll
    for (int r = 0; r < 16; r++) {
      float pv = fexp2(fmaf(s[r], C2f, nb));
      p[r] = ((mh >> ((r & 3) + 8 * (r >> 2))) & 1u) ? pv : 0.f;
    }
    float rsa = (p[0] + p[1]) + (p[2] + p[3]);
    float rsb = (p[4] + p[5]) + (p[6] + p[7]);
    float rsc = (p[8] + p[9]) + (p[10] + p[11]);
    float rsd = (p[12] + p[13]) + (p[14] + p[15]);
    float rs = (rsa + rsb) + (rsc + rsd);
    rs += __shfl_xor(rs, 32);
    lrun += rs;

    unsigned wd[8];
    #pragma unroll
    for (int i = 0; i < 8; i++) wd[i] = cvtpk(p[2 * i], p[2 * i + 1]);
    plswap(wd[0], wd[2]); plswap(wd[1], wd[3]);
    plswap(wd[4], wd[6]); plswap(wd[5], wd[7]);
    union { unsigned u[4]; bf16x8 v; } U0, U1;
    U0.u[0] = wd[0]; U0.u[1] = wd[1]; U0.u[2] = wd[2]; U0.u[3] = wd[3];
    U1.u[0] = wd[4]; U1.u[1] = wd[5]; U1.u[2] = wd[6]; U1.u[3] = wd[7];

    // ---- PV ----
    acc0 = MFMA32(vf[0], U0.v, acc0);
    acc0 = MFMA32(vf[1], U1.v, acc0);
    acc1 = MFMA32(vf[2], U0.v, acc1);
    acc1 = MFMA32(vf[3], U1.v, acc1);
    if (it < 15) loadV(ti + 1);      // vf dead: prefetch next V under next QK+softmax
  }

  // ---- 4-way merge ----
  if (w) {
    #pragma unroll
    for (int i = 0; i < 16; i++) { mbuf[w-1][lane][i] = acc0[i]; mbuf[w-1][lane][16 + i] = acc1[i]; }
    mbuf[w-1][lane][32] = mrun; mbuf[w-1][lane][33] = lrun;
  }
  __syncthreads();
  if (!w) {
    float mo[3], lo[3];
    #pragma unroll
    for (int wv = 0; wv < 3; wv++) { mo[wv] = mbuf[wv][lane][32]; lo[wv] = mbuf[wv][lane][33]; }
    float mN = fmaxf(fmaxf(mrun, mo[0]), fmaxf(mo[1], mo[2]));
    float sf0 = fexp2((mrun - mN) * C2f);
    float sfv[3];
    float lsum = lrun * sf0;
    #pragma unroll
    for (int wv = 0; wv < 3; wv++) { sfv[wv] = fexp2((mo[wv] - mN) * C2f); lsum += lo[wv] * sfv[wv]; }
    float linv = 1.f / lsum;
    float a2[32];
    #pragma unroll
    for (int i = 0; i < 16; i++) {
      float v0 = acc0[i] * sf0, v1 = acc1[i] * sf0;
      #pragma unroll
      for (int wv = 0; wv < 3; wv++) {
        v0 += mbuf[wv][lane][i] * sfv[wv];
        v1 += mbuf[wv][lane][16 + i] * sfv[wv];
      }
      a2[i] = v0 * linv;
      a2[16 + i] = v1 * linv;
    }
    // transpose O^T[d][q] -> O[q][d] via LDS (stride 72 shorts, 16B-aligned rows)
    unsigned short* ot = (unsigned short*)&mbuf[0][0][0];
    #pragma unroll
    for (int d2 = 0; d2 < 2; d2++)
      #pragma unroll
      for (int i = 0; i < 8; i++) {
        int d0 = ((2 * i) & 3) + 8 * (i >> 1) + 4 * hi + 32 * d2;
        unsigned wv2 = cvtpk(a2[d2 * 16 + 2 * i], a2[d2 * 16 + 2 * i + 1]);
        *(unsigned*)(ot + q5 * 72 + d0) = wv2;
      }
    #pragma unroll
    for (int it2 = 0; it2 < 4; ++it2) {
      int row = (lane >> 3) + it2 * 8, ch = lane & 7;
      uint4 val = *(const uint4*)(ot + row * 72 + ch * 8);
      *(uint4*)(O + ((size_t)(b * 2048 + q0 + row)) * 512 + h * 64 + ch * 8) = val;
    }
  }
}

// ---------------- host ----------------
extern "C" void kernel_launch(void* const* d_in, const int* in_sizes, int n_in,
                              void* d_out, int out_size, void* d_ws, size_t ws_size,
                              hipStream_t stream) {
  const float* x     = (const float*)d_in[0];
  const float* ctx   = (const float*)d_in[1];
  const int*   mask  = (const int*)d_in[2];
  const float* ln_g  = (const float*)d_in[3];
  const float* ln_b  = (const float*)d_in[4];
  const float* Wq    = (const float*)d_in[5];
  const float* Wkv   = (const float*)d_in[6];
  const float* Wo    = (const float*)d_in[7];
  const float* lno_g = (const float*)d_in[8];
  const float* lno_b = (const float*)d_in[9];
  float* out = (float*)d_out;

  char* ws = (char*)d_ws;
  unsigned short* WqT  = (unsigned short*)(ws + 0);                         // 512 KB
  unsigned short* WkvT = (unsigned short*)(ws + (size_t)1 * (1 << 19));     // 1 MB
  unsigned short* WoT  = (unsigned short*)(ws + (size_t)3 * (1 << 19));     // 512 KB
  unsigned short* xn   = (unsigned short*)(ws + (size_t)2  * (1 << 20));    // 4 MB
  unsigned short* cb   = (unsigned short*)(ws + (size_t)6  * (1 << 20));    // 4 MB
  unsigned short* Qp   = (unsigned short*)(ws + (size_t)10 * (1 << 20));    // 4 MB (fragment-packed)
  unsigned short* Kp   = (unsigned short*)(ws + (size_t)14 * (1 << 20));    // 4 MB (fragment-packed)
  unsigned short* Vp   = (unsigned short*)(ws + (size_t)18 * (1 << 20));    // 4 MB (fragment-packed)
  unsigned short* ao   = (unsigned short*)(ws + (size_t)22 * (1 << 20));    // 4 MB
  float* proj          = (float*)(ws + (size_t)26 * (1 << 20));             // 8 MB
  unsigned int* mbw    = (unsigned int*)(ws + (size_t)26 * (1 << 20));      // 512 B, overlaps proj (dead by then)

  k_prep<<<4112, 256, 0, stream>>>(Wq, Wkv, Wo, x, ln_g, ln_b, ctx, mask,
                                   WqT, WkvT, WoT, xn, cb, mbw);
  k_qkv<<<768, 256, 0, stream>>>(xn, WqT, Qp, cb, WkvT, Kp, Vp);
  k_attn<<<1024, 256, 0, stream>>>(Qp, Kp, Vp, mbw, ao);
  k_oproj<<<256, 256, 0, stream>>>(ao, WoT, proj);
  k_layernorm_f<<<1024, 256, 0, stream>>>(proj, lno_g, lno_b, out);
}